// Round 11
// baseline (420.545 us; speedup 1.0000x reference)
//
#include <hip/hip_runtime.h>
#include <math.h>

// ---- problem constants (from reference) ----
constexpr int B_  = 4;
constexpr int S_  = 4096;
constexpr int D_  = 1024;   // DIM
constexpr int IN_ = 2048;   // INNER
constexpr float EPS_ = 1e-8f;
constexpr int NCH_ = 128;         // chunks per sequence for the scan
constexpr int CS_  = S_ / NCH_;   // 32 timesteps per chunk
constexpr float LOG2E_ = 1.4426950408889634f;
constexpr float LN2_   = 0.6931471805599453f;
constexpr float EPS2_  = 1.4426950408889634e-8f;   // EPS * log2(e)

typedef __attribute__((ext_vector_type(8))) _Float16 f16x8;
typedef __attribute__((ext_vector_type(2))) _Float16 h2;
typedef __attribute__((ext_vector_type(4))) float    f32x4;

#define BAR() asm volatile("s_barrier" ::: "memory")

// ---- helpers ----
__device__ __forceinline__ h2 pkrtz(float a, float b) {
  auto r = __builtin_amdgcn_cvt_pkrtz(a, b);
  union { decltype(r) r_; h2 h; } c; c.r_ = r; return c.h;
}
__device__ __forceinline__ unsigned packh2(float a, float b) {
  auto r = __builtin_amdgcn_cvt_pkrtz(a, b);
  union { decltype(r) r_; unsigned u; } c; c.r_ = r; return c.u;
}
__device__ __forceinline__ void unpack_h8(uint4 v, float* f) {
  union { uint4 u; _Float16 h[8]; } c; c.u = v;
  #pragma unroll
  for (int i = 0; i < 8; ++i) f[i] = (float)c.h[i];
}
// base-2 softplus: sp2(t) = max(t,0) + log2(1 + 2^-|t|)
__device__ __forceinline__ float sp2(float t) {
  const float e = __builtin_amdgcn_exp2f(-fabsf(t));
  return fmaxf(t, 0.0f) + __builtin_amdgcn_logf(1.0f + e);
}
__device__ __forceinline__ float siluf(float x) {
  return x * __builtin_amdgcn_rcpf(1.0f + __builtin_amdgcn_exp2f(-x * LOG2E_));
}

// async global->LDS, 16 B per lane (wave-uniform LDS base + lane*16)
__device__ __forceinline__ void gload16(const void* g, void* l) {
  __builtin_amdgcn_global_load_lds(
      (const __attribute__((address_space(1))) void*)g,
      (__attribute__((address_space(3))) void*)l,
      16, 0, 0);
}

// ---------------------------------------------------------------------------
// fp32 -> f16 conversion for two buffers in one launch (8 elems/thread)
// ---------------------------------------------------------------------------
__launch_bounds__(256)
__global__ void cvt_f16_2(const float* __restrict__ in0, unsigned* __restrict__ out0,
                          long n8_0,
                          const float* __restrict__ in1, unsigned* __restrict__ out1,
                          long n8_1)
{
  const long total  = n8_0 + n8_1;
  const long stride = (long)gridDim.x * blockDim.x;
  for (long t = (long)blockIdx.x * blockDim.x + threadIdx.x; t < total; t += stride) {
    const float* in  = (t < n8_0) ? in0  : in1;
    unsigned*    out = (t < n8_0) ? out0 : out1;
    const long   i   = (t < n8_0) ? t    : t - n8_0;
    const float4 a = *(const float4*)(in + i * 8);
    const float4 b = *(const float4*)(in + i * 8 + 4);
    uint4 o;
    o.x = packh2(a.x, a.y);
    o.y = packh2(a.z, a.w);
    o.z = packh2(b.x, b.y);
    o.w = packh2(b.z, b.w);
    *(uint4*)(out + i * 4) = o;
  }
}

__launch_bounds__(256)
__global__ void cvt_f16(const float* __restrict__ in, unsigned* __restrict__ outp,
                        long n8)
{
  const long stride = (long)gridDim.x * blockDim.x;
  for (long i = (long)blockIdx.x * blockDim.x + threadIdx.x; i < n8; i += stride) {
    const float4 a = *(const float4*)(in + i * 8);
    const float4 b = *(const float4*)(in + i * 8 + 4);
    uint4 o;
    o.x = packh2(a.x, a.y);
    o.y = packh2(a.z, a.w);
    o.z = packh2(b.x, b.y);
    o.w = packh2(b.z, b.w);
    *(uint4*)(outp + i * 4) = o;
  }
}

// ---------------------------------------------------------------------------
// f16 MFMA NT GEMM, 128x256 tile, BK=32, TRIPLE-buffered LDS (72 KB ->
// 2 blocks/CU for cross-block latency hiding), 8 waves (2M x 4N), per-wave
// 64x64 output (64 acc VGPRs), XOR swizzle colblk^=(row>>1)&3 (2 lanes/bank,
// free), counted vmcnt(3), setprio, bijective XCD swizzle.
// Per K-tile: stage t+2 into buf[(t+2)%3] || 8 ds_read_b128 -> barrier ->
// 16 MFMA -> vmcnt(3) -> barrier.  No phase splitting needed: prefetch
// target never aliases the read buffer (t+2 == t-1 mod 3, drained).
// MODE 0: split epilogue -> xmin(f16) | silu(z)(f16) via per-wave LDS
//         transpose (16B full-line stores).   MODE 1: fp32 direct stores.
// ---------------------------------------------------------------------------
template<int MODE>
__launch_bounds__(512, 4)
__global__ void gemm_mfma(const unsigned short* __restrict__ Ab,
                          const unsigned short* __restrict__ Bb,
                          const float* __restrict__ bias,
                          void* __restrict__ out0,
                          unsigned short* __restrict__ out1,
                          int M, int N, int K)
{
  constexpr int BM = 128, BN = 256, BK = 32;
  // single region: A bufs at [b*4096], B bufs at [12288 + b*8192] (f16 units)
  __shared__ __align__(16) unsigned short Ls[3 * BM * BK + 3 * BN * BK]; // 73728 B

  const int tid  = threadIdx.x;
  const int lane = tid & 63;
  const int w    = tid >> 6;       // 0..7
  const int wm   = w >> 2;         // 0..1  (M half, 64 rows each)
  const int wn   = w & 3;          // 0..3  (N quarter, 64 cols each)

  // bijective XCD swizzle
  const int GX  = gridDim.x;
  const int nwg = GX * gridDim.y;           // divisible by 8 for our shapes
  int lin = blockIdx.y * GX + blockIdx.x;
  lin = (lin & 7) * (nwg >> 3) + (lin >> 3);
  const int m0 = (lin / GX) * BM;
  const int n0 = (lin % GX) * BN;
  const int NT = K / BK;

  // staging geometry: one gload16 covers 16 rows (4 lanes/row, 8 f16/lane)
  const int sr2  = lane >> 2;                        // 0..15 row-in-call
  const int sblk = ((lane & 3) ^ ((lane >> 3) & 3)) * 8;  // pre-swizzled col

  // fragment read geometry: colblk = (lane>>4) ^ ((row>>1)&3), row=base+fr
  const int fr  = lane & 15;
  const int fcb = (((lane >> 4) ^ ((lane >> 1) & 3))) * 8;

  auto stageA = [&](int buf, int kOff) {
    gload16(Ab + (size_t)(m0 + w * 16 + sr2) * K + kOff + sblk,
            &Ls[buf * (BM * BK) + (w * 16) * BK]);
  };
  auto stageB = [&](int buf, int kOff) {
    gload16(Bb + (size_t)(n0 + w * 16 + sr2) * K + kOff + sblk,
            &Ls[3 * BM * BK + buf * (BN * BK) + (w * 16) * BK]);
    gload16(Bb + (size_t)(n0 + 128 + w * 16 + sr2) * K + kOff + sblk,
            &Ls[3 * BM * BK + buf * (BN * BK) + (128 + w * 16) * BK]);
  };

  f32x4 acc[4][4] = {};

  // ---- prologue: stage tiles 0 and 1 (3 calls each per wave) ----
  stageA(0, 0);  stageB(0, 0);
  stageA(1, BK); stageB(1, BK);
  asm volatile("s_waitcnt vmcnt(3)" ::: "memory");   // tile 0 landed
  BAR();

  int bufc = 0;
  for (int t = 0; t < NT; ++t) {
    const unsigned short* AL = &Ls[bufc * (BM * BK)];
    const unsigned short* BL = &Ls[3 * BM * BK + bufc * (BN * BK)];
    const int bufn = (bufc + 2 >= 3) ? bufc - 1 : bufc + 2;  // (t+2)%3

    // stage tile t+2 (target buffer drained at end of tile t-1)
    if (t + 2 < NT) {
      stageA(bufn, (t + 2) * BK);
      stageB(bufn, (t + 2) * BK);
    }

    // fragment reads (compiler inserts lgkm waits before MFMA use)
    f16x8 af[4], bf[4];
    #pragma unroll
    for (int i = 0; i < 4; ++i)
      af[i] = *(const f16x8*)&AL[(wm * 64 + i * 16 + fr) * BK + fcb];
    #pragma unroll
    for (int j = 0; j < 4; ++j)
      bf[j] = *(const f16x8*)&BL[(wn * 64 + j * 16 + fr) * BK + fcb];

    BAR();
    __builtin_amdgcn_s_setprio(1);
    #pragma unroll
    for (int i = 0; i < 4; ++i)
      #pragma unroll
      for (int j = 0; j < 4; ++j)
        acc[i][j] = __builtin_amdgcn_mfma_f32_16x16x32_f16(af[i], bf[j], acc[i][j], 0, 0, 0);
    __builtin_amdgcn_s_setprio(0);
    // tile t+1's batch (3 calls, issued at t-1) must land; t+2's 3 may remain
    if (t + 2 < NT) asm volatile("s_waitcnt vmcnt(3)" ::: "memory");
    else            asm volatile("s_waitcnt vmcnt(0)" ::: "memory");
    BAR();
    bufc = (bufc + 1 >= 3) ? 0 : bufc + 1;
  }

  // ---- epilogue ----
  const int col = lane & 15;
  const int rb4 = (lane >> 4) * 4;

  if (MODE == 1) {
    // fp32 direct stores: lanes 0-15 cover 64B contiguous per row
    #pragma unroll
    for (int j = 0; j < 4; ++j) {
      const int n  = n0 + wn * 64 + j * 16 + col;
      const float bv = bias[n];
      #pragma unroll
      for (int i = 0; i < 4; ++i) {
        const int mb = m0 + wm * 64 + i * 16 + rb4;
        #pragma unroll
        for (int r = 0; r < 4; ++r)
          ((float*)out0)[(size_t)(mb + r) * N + n] = acc[i][j][r] + bv;
      }
    }
  } else {
    // f16 split outputs via per-wave LDS transpose -> 16B full-line stores.
    // 2 passes x 32 rows; wave-private slice 32 x RS(=72) f16 = 4608 B.
    BAR();   // ensure all waves' pending LDS reads drained before reuse
    constexpr int RS = 72;
    unsigned short* eb = Ls + w * (32 * RS);
    const bool zhalf = (n0 >= IN_);   // block-uniform (IN_ % 256 == 0)
    float bv[4];
    #pragma unroll
    for (int j = 0; j < 4; ++j) bv[j] = bias[n0 + wn * 64 + j * 16 + col];

    const int lrow = lane >> 3;       // 0..7
    const int lc8  = (lane & 7) * 8;  // 0..56
    unsigned short* dst = zhalf ? out1 : (unsigned short*)out0;
    const int ncol0 = (zhalf ? n0 - IN_ : n0) + wn * 64 + lc8;

    #pragma unroll
    for (int p = 0; p < 2; ++p) {
      asm volatile("s_waitcnt lgkmcnt(0)" ::: "memory");  // slice reusable
      #pragma unroll
      for (int i2 = 0; i2 < 2; ++i2)
        #pragma unroll
        for (int j = 0; j < 4; ++j)
          #pragma unroll
          for (int r = 0; r < 4; ++r) {
            const float v = acc[p * 2 + i2][j][r] + bv[j];
            ((_Float16*)eb)[(i2 * 16 + rb4 + r) * RS + j * 16 + col] = (_Float16)v;
          }
      asm volatile("s_waitcnt lgkmcnt(0)" ::: "memory");
      #pragma unroll
      for (int it = 0; it < 4; ++it) {
        const int row = it * 8 + lrow;
        uint4 d = *(const uint4*)&eb[row * RS + lc8];
        if (zhalf) {
          float f[8];
          unpack_h8(d, f);
          d.x = packh2(siluf(f[0]), siluf(f[1]));
          d.y = packh2(siluf(f[2]), siluf(f[3]));
          d.z = packh2(siluf(f[4]), siluf(f[5]));
          d.w = packh2(siluf(f[6]), siluf(f[7]));
        }
        const int m = m0 + wm * 64 + p * 32 + row;
        *(uint4*)(dst + (size_t)m * IN_ + ncol0) = d;
      }
    }
  }
}

// ---------------------------------------------------------------------------
// causal depthwise conv (K=4, left pad 3) + SiLU.  f16 in/out.
// 8 channels x 4 timesteps per thread: 7 row-loads for 4 outputs.
// ---------------------------------------------------------------------------
__launch_bounds__(256)
__global__ void conv_silu_k(const uint4* __restrict__ xm,
                            const float* __restrict__ cw,   // (IN_,1,4)
                            const float* __restrict__ cb,
                            uint4* __restrict__ act)
{
  const int t = blockIdx.x * 256 + threadIdx.x;   // grid sized exactly
  const int c8 = t & 255;                         // channel group (IN_/8)
  const int s4 = (t >> 8) & (S_ / 4 - 1);         // timestep group
  const int b  = t >> 18;
  const int c  = c8 * 8;
  constexpr int RW = IN_ / 8;                     // row stride in uint4

  float w[8][4];
  #pragma unroll
  for (int j = 0; j < 8; ++j)
    *(float4*)w[j] = *(const float4*)(cw + (size_t)(c + j) * 4);
  float bias8[8];
  *(float4*)(bias8)     = *(const float4*)(cb + c);
  *(float4*)(bias8 + 4) = *(const float4*)(cb + c + 4);

  const size_t rowb = ((size_t)b * S_ + s4 * 4) * RW + c8;  // row s4*4
  float xf[7][8];
  #pragma unroll
  for (int i = 0; i < 7; ++i) {
    if (s4 == 0 && i < 3) {
      #pragma unroll
      for (int j = 0; j < 8; ++j) xf[i][j] = 0.0f;
    } else {
      unpack_h8(xm[rowb + (long)(i - 3) * RW], xf[i]);
    }
  }

  #pragma unroll
  for (int o = 0; o < 4; ++o) {
    float r[8];
    #pragma unroll
    for (int j = 0; j < 8; ++j) r[j] = bias8[j];
    #pragma unroll
    for (int k = 0; k < 4; ++k)
      #pragma unroll
      for (int j = 0; j < 8; ++j)
        r[j] = fmaf(xf[o + k][j], w[j][k], r[j]);
    uint4 ov;
    ov.x = packh2(siluf(r[0]), siluf(r[1]));
    ov.y = packh2(siluf(r[2]), siluf(r[3]));
    ov.z = packh2(siluf(r[4]), siluf(r[5]));
    ov.w = packh2(siluf(r[6]), siluf(r[7]));
    act[rowb + (size_t)o * RW] = ov;
  }
}

// ---------------------------------------------------------------------------
// grouped 16x16 gate projections + per-chunk scan partials, base-2 log domain.
// ---------------------------------------------------------------------------
__launch_bounds__(256)
__global__ void gates_scan(const unsigned* __restrict__ actb,
                           const float* __restrict__ wf,
                           const float* __restrict__ wi,
                           const float* __restrict__ wh,
                           float2* __restrict__ part)   // [B_*IN_][NCH_]
{
  const int T  = blockIdx.x * 256 + threadIdx.x;
  const int o  = T & 15;
  const int g  = (T >> 4) & 127;
  const int ck = (T >> 11) & (NCH_ - 1);
  const int b  = T >> 18;

  h2 Wf2[8], Wi2[8], Wh2[8];
  const float* pf = wf + ((size_t)g * 16 + o) * 16;
  const float* pi = wi + ((size_t)g * 16 + o) * 16;
  const float* ph = wh + ((size_t)g * 16 + o) * 16;
  #pragma unroll
  for (int i = 0; i < 8; ++i) {
    Wf2[i] = pkrtz(pf[2 * i] * LOG2E_, pf[2 * i + 1] * LOG2E_);
    Wi2[i] = pkrtz(pi[2 * i] * LOG2E_, pi[2 * i + 1] * LOG2E_);
    Wh2[i] = pkrtz(ph[2 * i], ph[2 * i + 1]);
  }

  float p = 0.0f, Mx = -INFINITY, Ss = 0.0f;
  const unsigned* ap = actb + ((size_t)b * S_ + (size_t)ck * CS_) * (IN_ / 2) + g * 8;
  for (int s = 0; s < CS_; ++s) {
    union { uint4 u; h2 h[4]; } A0, A1;
    A0.u = *(const uint4*)(ap);
    A1.u = *(const uint4*)(ap + 4);
    ap += IN_ / 2;
    float fg = 0.0f, ig = 0.0f, hd = 0.0f;   // fg, ig in base-2 units
    #pragma unroll
    for (int i = 0; i < 4; ++i) {
      fg = __builtin_amdgcn_fdot2(A0.h[i], Wf2[i], fg, false);
      ig = __builtin_amdgcn_fdot2(A0.h[i], Wi2[i], ig, false);
      hd = __builtin_amdgcn_fdot2(A0.h[i], Wh2[i], hd, false);
    }
    #pragma unroll
    for (int i = 0; i < 4; ++i) {
      fg = __builtin_amdgcn_fdot2(A1.h[i], Wf2[i + 4], fg, false);
      ig = __builtin_amdgcn_fdot2(A1.h[i], Wi2[i + 4], ig, false);
      hd = __builtin_amdgcn_fdot2(A1.h[i], Wh2[i + 4], hd, false);
    }
    const float diff  = sp2(-fg) - sp2(-ig);
    const float log_f = -sp2(diff);
    const float log_i = diff + log_f;
    const float lpos  = __builtin_amdgcn_logf(hd + 0.5f + EPS_);
    const float lneg  = -sp2(-hd * LOG2E_) + EPS2_;
    const float log_th = (hd >= 0.0f) ? lpos : lneg;
    p += log_f + EPS2_;
    const float v = log_i + log_th - p;
    const float m = fmaxf(Mx, v);
    Ss = Ss * __builtin_amdgcn_exp2f(Mx - m) + __builtin_amdgcn_exp2f(v - m);
    Mx = m;
  }
  part[((size_t)(b * IN_ + g * 16 + o)) * NCH_ + ck] =
      make_float2(p, Mx + __builtin_amdgcn_logf(Ss));
}

// ---------------------------------------------------------------------------
// combine chunk partials -> h_last[b, c]   (base-2 domain throughout)
// ---------------------------------------------------------------------------
__launch_bounds__(256)
__global__ void combine_k(const float2* __restrict__ part, float* __restrict__ hlast)
{
  const int seq = blockIdx.x * 256 + threadIdx.x;
  if (seq >= B_ * IN_) return;
  const float2* pp = part + (size_t)seq * NCH_;
  float P = 0.0f, Mx = -INFINITY, Ss = 0.0f;
  for (int c = 0; c < NCH_; ++c) {
    const float2 al = pp[c];
    const float v = al.y - P;
    const float m = fmaxf(Mx, v);
    Ss = Ss * __builtin_amdgcn_exp2f(Mx - m) + __builtin_amdgcn_exp2f(v - m);
    Mx = m;
    P += al.x;
  }
  hlast[seq] = __builtin_amdgcn_exp2f(P + Mx) * Ss;
}

// ---------------------------------------------------------------------------
// G = (h_last + skip*act) * silu(z), written in place over the z buffer.
// ---------------------------------------------------------------------------
__launch_bounds__(256)
__global__ void gfuse_k(const unsigned* __restrict__ actb,
                        unsigned* __restrict__ zb,
                        const float* __restrict__ hlast,
                        const float* __restrict__ skipv)
{
  const size_t total  = (size_t)B_ * S_ * IN_ / 8;
  const size_t stride = (size_t)gridDim.x * blockDim.x;
  for (size_t t = (size_t)blockIdx.x * blockDim.x + threadIdx.x; t < total; t += stride) {
    const size_t e = t * 8;
    const int    c = (int)(e % IN_);
    const int    b = (int)(e / ((size_t)S_ * IN_));
    float a[8], z[8], hl[8], sk[8];
    unpack_h8(*(const uint4*)(actb + e / 2), a);
    unpack_h8(*(const uint4*)(zb   + e / 2), z);
    *(float4*)(hl)     = *(const float4*)(hlast + (size_t)b * IN_ + c);
    *(float4*)(hl + 4) = *(const float4*)(hlast + (size_t)b * IN_ + c + 4);
    *(float4*)(sk)     = *(const float4*)(skipv + c);
    *(float4*)(sk + 4) = *(const float4*)(skipv + c + 4);
    float g[8];
    #pragma unroll
    for (int j = 0; j < 8; ++j) g[j] = (hl[j] + sk[j] * a[j]) * z[j];
    uint4 o;
    o.x = packh2(g[0], g[1]);
    o.y = packh2(g[2], g[3]);
    o.z = packh2(g[4], g[5]);
    o.w = packh2(g[6], g[7]);
    *(uint4*)(zb + e / 2) = o;
  }
}

// ---------------------------------------------------------------------------
extern "C" void kernel_launch(void* const* d_in, const int* in_sizes, int n_in,
                              void* d_out, int out_size, void* d_ws, size_t ws_size,
                              hipStream_t stream)
{
  const float* x     = (const float*)d_in[0];
  const float* w_up  = (const float*)d_in[1];
  const float* b_up  = (const float*)d_in[2];
  const float* cw    = (const float*)d_in[3];
  const float* cb    = (const float*)d_in[4];
  const float* skipv = (const float*)d_in[5];
  const float* w_f   = (const float*)d_in[6];
  const float* w_i   = (const float*)d_in[7];
  const float* w_h   = (const float*)d_in[8];
  const float* w_dn  = (const float*)d_in[9];
  const float* b_dn  = (const float*)d_in[10];
  float* out = (float*)d_out;

  // workspace layout with lifetime-based aliasing (max ~210 MB)
  char* ws = (char*)d_ws;
  unsigned short* xminb = (unsigned short*)(ws);
  unsigned short* wdb   = (unsigned short*)(ws);                    // after conv
  float2*         part  = (float2*)(ws + 8388608ULL);               // after conv
  float*          hlast = (float*)(ws + 16777216ULL);               // after conv
  unsigned short* zb    = (unsigned short*)(ws + 67108864ULL);
  unsigned short* actb  = (unsigned short*)(ws + 134217728ULL);
  unsigned short* xb    = (unsigned short*)(ws + 134217728ULL);     // pre-conv alias
  unsigned short* wub   = (unsigned short*)(ws + 201326592ULL);

  const int M = B_ * S_;   // 16384

  // 0) fp32 -> f16 conversions for MFMA operands (single launch)
  cvt_f16_2<<<2560, 256, 0, stream>>>(
      x,    (unsigned*)xb,  (long)M * D_ / 8,
      w_up, (unsigned*)wub, (long)2 * IN_ * D_ / 8);

  // 1) proj-up: xb @ wub^T + b_up -> xmin(f16) | silu(z)(f16)
  gemm_mfma<0><<<dim3((2 * IN_) / 256, M / 128), 512, 0, stream>>>(
      xb, wub, b_up, xminb, (unsigned short*)zb, M, 2 * IN_, D_);

  // 2) causal depthwise conv + SiLU -> act(f16)  (4 steps x 8 ch / thread)
  conv_silu_k<<<(B_ * (S_ / 4) * (IN_ / 8)) / 256, 256, 0, stream>>>(
      (const uint4*)xminb, cw, cb, (uint4*)actb);

  // 2b) w_down -> f16 (into region freed by xminb)
  cvt_f16<<<256, 256, 0, stream>>>(w_dn, (unsigned*)wdb, (long)D_ * IN_ / 8);

  // 3) grouped gate projections + chunked scan partials
  gates_scan<<<(B_ * 128 * 16 * NCH_) / 256, 256, 0, stream>>>(
      (const unsigned*)actb, w_f, w_i, w_h, part);

  // 4) combine partials -> h_last
  combine_k<<<(B_ * IN_ + 255) / 256, 256, 0, stream>>>(part, hlast);

  // 5) G = (h_last + skip*act) * silu(z), in place over zb
  gfuse_k<<<2048, 256, 0, stream>>>((const unsigned*)actb, (unsigned*)zb, hlast, skipv);

  // 6) proj-down: G(f16) @ wdb^T + b_dn -> out (fp32)
  gemm_mfma<1><<<dim3(D_ / 256, M / 128), 512, 0, stream>>>(
      zb, wdb, b_dn, out, nullptr, M, D_, IN_);
}

// Round 12
// 414.929 us; speedup vs baseline: 1.0135x; 1.0135x over previous
//
#include <hip/hip_runtime.h>
#include <math.h>

// ---- problem constants (from reference) ----
constexpr int B_  = 4;
constexpr int S_  = 4096;
constexpr int D_  = 1024;   // DIM
constexpr int IN_ = 2048;   // INNER
constexpr float EPS_ = 1e-8f;
constexpr int NCH_ = 128;         // chunks per sequence for the scan
constexpr int CS_  = S_ / NCH_;   // 32 timesteps per chunk
constexpr float LOG2E_ = 1.4426950408889634f;
constexpr float EPS2_  = 1.4426950408889634e-8f;   // EPS * log2(e)

typedef __attribute__((ext_vector_type(8))) _Float16 f16x8;
typedef __attribute__((ext_vector_type(2))) _Float16 h2;
typedef __attribute__((ext_vector_type(4))) float    f32x4;

#define BAR() asm volatile("s_barrier" ::: "memory")

// ---- helpers ----
__device__ __forceinline__ h2 pkrtz(float a, float b) {
  auto r = __builtin_amdgcn_cvt_pkrtz(a, b);
  union { decltype(r) r_; h2 h; } c; c.r_ = r; return c.h;
}
__device__ __forceinline__ unsigned packh2(float a, float b) {
  auto r = __builtin_amdgcn_cvt_pkrtz(a, b);
  union { decltype(r) r_; unsigned u; } c; c.r_ = r; return c.u;
}
__device__ __forceinline__ void unpack_h8(uint4 v, float* f) {
  union { uint4 u; _Float16 h[8]; } c; c.u = v;
  #pragma unroll
  for (int i = 0; i < 8; ++i) f[i] = (float)c.h[i];
}
// base-2 softplus: sp2(t) = max(t,0) + log2(1 + 2^-|t|)
__device__ __forceinline__ float sp2(float t) {
  const float e = __builtin_amdgcn_exp2f(-fabsf(t));
  return fmaxf(t, 0.0f) + __builtin_amdgcn_logf(1.0f + e);
}
__device__ __forceinline__ float siluf(float x) {
  return x * __builtin_amdgcn_rcpf(1.0f + __builtin_amdgcn_exp2f(-x * LOG2E_));
}

// async global->LDS, 16 B per lane (wave-uniform LDS base + lane*16)
__device__ __forceinline__ void gload16(const void* g, void* l) {
  __builtin_amdgcn_global_load_lds(
      (const __attribute__((address_space(1))) void*)g,
      (__attribute__((address_space(3))) void*)l,
      16, 0, 0);
}

// ---------------------------------------------------------------------------
// fp32 -> f16 conversion (8 elems/thread)
// ---------------------------------------------------------------------------
__launch_bounds__(256)
__global__ void cvt_f16(const float* __restrict__ in, unsigned* __restrict__ outp,
                        long n8)
{
  const long stride = (long)gridDim.x * blockDim.x;
  for (long i = (long)blockIdx.x * blockDim.x + threadIdx.x; i < n8; i += stride) {
    const float4 a = *(const float4*)(in + i * 8);
    const float4 b = *(const float4*)(in + i * 8 + 4);
    uint4 o;
    o.x = packh2(a.x, a.y);
    o.y = packh2(a.z, a.w);
    o.z = packh2(b.x, b.y);
    o.w = packh2(b.z, b.w);
    *(uint4*)(outp + i * 4) = o;
  }
}

// ---------------------------------------------------------------------------
// repack weight matrix (N x K fp32, row-major) into MFMA-fragment-ordered
// f16 tiles of 1 KB: tile (nt = n/16, kt = k/32), slot l (0..63) holds
// B[nt*16 + (l&15)][kt*32 + 8*(l>>4) .. +8].  One thread per 16B slot.
// In the GEMM, each wave's B-fragment load = one coalesced 1 KB read (L2-hot).
// ---------------------------------------------------------------------------
__launch_bounds__(256)
__global__ void pack_b(const float* __restrict__ w, uint4* __restrict__ bp, int K)
{
  const int t    = blockIdx.x * 256 + threadIdx.x;   // grid sized exactly
  const int l    = t & 63;
  const int tile = t >> 6;
  const int KT   = K >> 5;
  const int nt   = tile / KT;
  const int kt   = tile - nt * KT;
  const float* src = w + (size_t)(nt * 16 + (l & 15)) * K + kt * 32 + ((l >> 4) << 3);
  const float4 a = *(const float4*)src;
  const float4 b = *(const float4*)(src + 4);
  uint4 o;
  o.x = packh2(a.x, a.y);
  o.y = packh2(a.z, a.w);
  o.z = packh2(b.x, b.y);
  o.w = packh2(b.z, b.w);
  bp[t] = o;
}

// ---------------------------------------------------------------------------
// f16 MFMA NT GEMM, B streamed from L2 (packed fragments), A in LDS.
// 128x256 tile, BK=64, 8 waves (2M x 4N), per-wave 64x64 (acc 64 regs).
// A: triple-buffered LDS 48 KB (2 gload16/wave/tile, XOR swizzle), counted
// vmcnt(2).  B: 8 x 1KB coalesced global loads per wave per tile (L2-resident
// by band-ordered XCD mapping: 8-panel bands = 4 MB working set).
// MODE 0: split epilogue -> xmin(f16) | silu(z)(f16) via per-wave LDS
//         transpose (16B full-line stores).   MODE 1: fp32 direct stores.
// ---------------------------------------------------------------------------
template<int MODE>
__launch_bounds__(512, 4)
__global__ void gemm_bl2(const unsigned short* __restrict__ Ab,
                         const unsigned short* __restrict__ Bp,
                         const float* __restrict__ bias,
                         void* __restrict__ out0,
                         unsigned short* __restrict__ out1,
                         int M, int N, int K)
{
  constexpr int BM = 128, BN = 256, BK = 64;
  __shared__ __align__(16) unsigned short Ls[3 * BM * BK];   // 48 KB

  const int tid  = threadIdx.x;
  const int lane = tid & 63;
  const int w    = tid >> 6;       // 0..7
  const int wm   = w >> 2;         // 0..1  (M half, 64 rows)
  const int wn   = w & 3;          // 0..3  (N quarter, 64 cols)

  // band-ordered XCD mapping: XCD owns CR consecutive m-panels; within it,
  // iterate n in bands of BW panels (B working set = BW * 512KB <= 4MB L2)
  const int GX  = gridDim.x;
  const int CR  = gridDim.y >> 3;
  const int BW  = (GX < 8) ? GX : 8;
  const int orig = blockIdx.y * GX + blockIdx.x;
  const int xcd = orig & 7, cl = orig >> 3;
  const int band = cl / (CR * BW);
  const int rr   = cl - band * (CR * BW);
  const int yl   = rr / BW;
  const int xin  = rr - yl * BW;
  const int m0 = (xcd * CR + yl) * BM;
  const int n0 = (band * BW + xin) * BN;
  const int NT = K / BK;
  const int KT = K >> 5;

  // A staging: one call = 8 rows x 64 cols; wave w covers rows w*16 .. +15
  const int sr   = lane >> 3;                   // 0..7
  const int sblk = ((lane & 7) ^ sr) * 8;       // pre-swizzled global col
  auto stageA = [&](int buf, int kOff) {
    gload16(Ab + (size_t)(m0 + w * 16 + sr) * K + kOff + sblk,
            &Ls[buf * (BM * BK) + (w * 16) * BK]);
    gload16(Ab + (size_t)(m0 + w * 16 + 8 + sr) * K + kOff + sblk,
            &Ls[buf * (BM * BK) + (w * 16 + 8) * BK]);
  };

  // A fragment read: row = wm*64 + i*16 + fr; col-block XOR (lane&7)
  const int fr  = lane & 15;
  const int fb0 = (((lane >> 4) + 0) ^ (lane & 7)) * 8;
  const int fb1 = (((lane >> 4) + 4) ^ (lane & 7)) * 8;

  const f16x8* Bpv = (const f16x8*)Bp;
  const int ntb = (n0 >> 4) + wn * 4;

  f32x4 acc[4][4] = {};

  // ---- prologue: stage A tiles 0 and 1 ----
  stageA(0, 0); stageA(1, BK);
  asm volatile("s_waitcnt vmcnt(2)" ::: "memory");   // tile 0 landed
  BAR();

  int bufc = 0;
  for (int t = 0; t < NT; ++t) {
    const unsigned short* AL = &Ls[bufc * (BM * BK)];
    const int  bufn = (bufc + 2 >= 3) ? bufc - 1 : bufc + 2;  // (t+2)%3
    const bool more = (t + 2 < NT);

    // B fragments straight from L2 (coalesced 1KB per load)
    f16x8 bf[4][2];
    #pragma unroll
    for (int j = 0; j < 4; ++j) {
      bf[j][0] = Bpv[((size_t)(ntb + j) * KT + 2 * t) * 64 + lane];
      bf[j][1] = Bpv[((size_t)(ntb + j) * KT + 2 * t + 1) * 64 + lane];
    }
    // stage A tile t+2 (its buffer was fully read by end of tile t-1)
    if (more) stageA(bufn, (t + 2) * BK);

    f16x8 af[4];
    #pragma unroll
    for (int i = 0; i < 4; ++i)
      af[i] = *(const f16x8*)&AL[(wm * 64 + i * 16 + fr) * BK + fb0];

    BAR();
    // bf + stageA(t+1) done; only stageA(t+2)'s 2 calls may remain in flight
    if (more) asm volatile("s_waitcnt vmcnt(2)" ::: "memory");
    else      asm volatile("s_waitcnt vmcnt(0)" ::: "memory");
    __builtin_amdgcn_s_setprio(1);
    #pragma unroll
    for (int i = 0; i < 4; ++i)
      #pragma unroll
      for (int j = 0; j < 4; ++j)
        acc[i][j] = __builtin_amdgcn_mfma_f32_16x16x32_f16(af[i], bf[j][0], acc[i][j], 0, 0, 0);
    __builtin_amdgcn_s_setprio(0);
    #pragma unroll
    for (int i = 0; i < 4; ++i)
      af[i] = *(const f16x8*)&AL[(wm * 64 + i * 16 + fr) * BK + fb1];
    __builtin_amdgcn_s_setprio(1);
    #pragma unroll
    for (int i = 0; i < 4; ++i)
      #pragma unroll
      for (int j = 0; j < 4; ++j)
        acc[i][j] = __builtin_amdgcn_mfma_f32_16x16x32_f16(af[i], bf[j][1], acc[i][j], 0, 0, 0);
    __builtin_amdgcn_s_setprio(0);
    BAR();
    bufc = (bufc + 1 >= 3) ? 0 : bufc + 1;
  }

  // ---- epilogue ----
  const int col = lane & 15;
  const int rb4 = (lane >> 4) * 4;

  if (MODE == 1) {
    // fp32 direct stores: lanes 0-15 cover 64B contiguous per row
    #pragma unroll
    for (int j = 0; j < 4; ++j) {
      const int n  = n0 + wn * 64 + j * 16 + col;
      const float bv = bias[n];
      #pragma unroll
      for (int i = 0; i < 4; ++i) {
        const int mb = m0 + wm * 64 + i * 16 + rb4;
        #pragma unroll
        for (int r = 0; r < 4; ++r)
          ((float*)out0)[(size_t)(mb + r) * N + n] = acc[i][j][r] + bv;
      }
    }
  } else {
    // f16 split outputs via per-wave LDS transpose -> 16B full-line stores.
    // 2 passes x 32 rows; wave-private slice 32 x RS(=72) f16 = 4608 B.
    BAR();   // all waves' pending LDS reads drained before reuse
    constexpr int RS = 72;
    unsigned short* eb = Ls + w * (32 * RS);
    const bool zhalf = (n0 >= IN_);   // block-uniform (256 | IN_)
    float bv[4];
    #pragma unroll
    for (int j = 0; j < 4; ++j) bv[j] = bias[n0 + wn * 64 + j * 16 + col];

    const int lrow = lane >> 3;       // 0..7
    const int lc8  = (lane & 7) * 8;  // 0..56
    unsigned short* dst = zhalf ? out1 : (unsigned short*)out0;
    const int ncol0 = (zhalf ? n0 - IN_ : n0) + wn * 64 + lc8;

    #pragma unroll
    for (int p = 0; p < 2; ++p) {
      asm volatile("s_waitcnt lgkmcnt(0)" ::: "memory");  // slice reusable
      #pragma unroll
      for (int i2 = 0; i2 < 2; ++i2)
        #pragma unroll
        for (int j = 0; j < 4; ++j)
          #pragma unroll
          for (int r = 0; r < 4; ++r) {
            const float v = acc[p * 2 + i2][j][r] + bv[j];
            ((_Float16*)eb)[(i2 * 16 + rb4 + r) * RS + j * 16 + col] = (_Float16)v;
          }
      asm volatile("s_waitcnt lgkmcnt(0)" ::: "memory");
      #pragma unroll
      for (int it = 0; it < 4; ++it) {
        const int row = it * 8 + lrow;
        uint4 d = *(const uint4*)&eb[row * RS + lc8];
        if (zhalf) {
          float f[8];
          unpack_h8(d, f);
          d.x = packh2(siluf(f[0]), siluf(f[1]));
          d.y = packh2(siluf(f[2]), siluf(f[3]));
          d.z = packh2(siluf(f[4]), siluf(f[5]));
          d.w = packh2(siluf(f[6]), siluf(f[7]));
        }
        const int m = m0 + wm * 64 + p * 32 + row;
        *(uint4*)(dst + (size_t)m * IN_ + ncol0) = d;
      }
    }
  }
}

// ---------------------------------------------------------------------------
// causal depthwise conv (K=4, left pad 3) + SiLU.  f16 in/out.
// 8 channels x 4 timesteps per thread: 7 row-loads for 4 outputs.
// ---------------------------------------------------------------------------
__launch_bounds__(256)
__global__ void conv_silu_k(const uint4* __restrict__ xm,
                            const float* __restrict__ cw,   // (IN_,1,4)
                            const float* __restrict__ cb,
                            uint4* __restrict__ act)
{
  const int t = blockIdx.x * 256 + threadIdx.x;   // grid sized exactly
  const int c8 = t & 255;                         // channel group (IN_/8)
  const int s4 = (t >> 8) & (S_ / 4 - 1);         // timestep group
  const int b  = t >> 18;
  const int c  = c8 * 8;
  constexpr int RW = IN_ / 8;                     // row stride in uint4

  float w[8][4];
  #pragma unroll
  for (int j = 0; j < 8; ++j)
    *(float4*)w[j] = *(const float4*)(cw + (size_t)(c + j) * 4);
  float bias8[8];
  *(float4*)(bias8)     = *(const float4*)(cb + c);
  *(float4*)(bias8 + 4) = *(const float4*)(cb + c + 4);

  const size_t rowb = ((size_t)b * S_ + s4 * 4) * RW + c8;
  float xf[7][8];
  #pragma unroll
  for (int i = 0; i < 7; ++i) {
    if (s4 == 0 && i < 3) {
      #pragma unroll
      for (int j = 0; j < 8; ++j) xf[i][j] = 0.0f;
    } else {
      unpack_h8(xm[rowb + (long)(i - 3) * RW], xf[i]);
    }
  }

  #pragma unroll
  for (int o = 0; o < 4; ++o) {
    float r[8];
    #pragma unroll
    for (int j = 0; j < 8; ++j) r[j] = bias8[j];
    #pragma unroll
    for (int k = 0; k < 4; ++k)
      #pragma unroll
      for (int j = 0; j < 8; ++j)
        r[j] = fmaf(xf[o + k][j], w[j][k], r[j]);
    uint4 ov;
    ov.x = packh2(siluf(r[0]), siluf(r[1]));
    ov.y = packh2(siluf(r[2]), siluf(r[3]));
    ov.z = packh2(siluf(r[4]), siluf(r[5]));
    ov.w = packh2(siluf(r[6]), siluf(r[7]));
    act[rowb + (size_t)o * RW] = ov;
  }
}

// ---------------------------------------------------------------------------
// grouped 16x16 gate projections + per-chunk scan partials, base-2 log domain.
// ---------------------------------------------------------------------------
__launch_bounds__(256)
__global__ void gates_scan(const unsigned* __restrict__ actb,
                           const float* __restrict__ wf,
                           const float* __restrict__ wi,
                           const float* __restrict__ wh,
                           float2* __restrict__ part)   // [B_*IN_][NCH_]
{
  const int T  = blockIdx.x * 256 + threadIdx.x;
  const int o  = T & 15;
  const int g  = (T >> 4) & 127;
  const int ck = (T >> 11) & (NCH_ - 1);
  const int b  = T >> 18;

  h2 Wf2[8], Wi2[8], Wh2[8];
  const float* pf = wf + ((size_t)g * 16 + o) * 16;
  const float* pi = wi + ((size_t)g * 16 + o) * 16;
  const float* ph = wh + ((size_t)g * 16 + o) * 16;
  #pragma unroll
  for (int i = 0; i < 8; ++i) {
    Wf2[i] = pkrtz(pf[2 * i] * LOG2E_, pf[2 * i + 1] * LOG2E_);
    Wi2[i] = pkrtz(pi[2 * i] * LOG2E_, pi[2 * i + 1] * LOG2E_);
    Wh2[i] = pkrtz(ph[2 * i], ph[2 * i + 1]);
  }

  float p = 0.0f, Mx = -INFINITY, Ss = 0.0f;
  const unsigned* ap = actb + ((size_t)b * S_ + (size_t)ck * CS_) * (IN_ / 2) + g * 8;
  for (int s = 0; s < CS_; ++s) {
    union { uint4 u; h2 h[4]; } A0, A1;
    A0.u = *(const uint4*)(ap);
    A1.u = *(const uint4*)(ap + 4);
    ap += IN_ / 2;
    float fg = 0.0f, ig = 0.0f, hd = 0.0f;   // fg, ig in base-2 units
    #pragma unroll
    for (int i = 0; i < 4; ++i) {
      fg = __builtin_amdgcn_fdot2(A0.h[i], Wf2[i], fg, false);
      ig = __builtin_amdgcn_fdot2(A0.h[i], Wi2[i], ig, false);
      hd = __builtin_amdgcn_fdot2(A0.h[i], Wh2[i], hd, false);
    }
    #pragma unroll
    for (int i = 0; i < 4; ++i) {
      fg = __builtin_amdgcn_fdot2(A1.h[i], Wf2[i + 4], fg, false);
      ig = __builtin_amdgcn_fdot2(A1.h[i], Wi2[i + 4], ig, false);
      hd = __builtin_amdgcn_fdot2(A1.h[i], Wh2[i + 4], hd, false);
    }
    const float diff  = sp2(-fg) - sp2(-ig);
    const float log_f = -sp2(diff);
    const float log_i = diff + log_f;
    const float lpos  = __builtin_amdgcn_logf(hd + 0.5f + EPS_);
    const float lneg  = -sp2(-hd * LOG2E_) + EPS2_;
    const float log_th = (hd >= 0.0f) ? lpos : lneg;
    p += log_f + EPS2_;
    const float v = log_i + log_th - p;
    const float m = fmaxf(Mx, v);
    Ss = Ss * __builtin_amdgcn_exp2f(Mx - m) + __builtin_amdgcn_exp2f(v - m);
    Mx = m;
  }
  part[((size_t)(b * IN_ + g * 16 + o)) * NCH_ + ck] =
      make_float2(p, Mx + __builtin_amdgcn_logf(Ss));
}

// ---------------------------------------------------------------------------
// combine chunk partials -> h_last[b, c]   (base-2 domain throughout)
// ---------------------------------------------------------------------------
__launch_bounds__(256)
__global__ void combine_k(const float2* __restrict__ part, float* __restrict__ hlast)
{
  const int seq = blockIdx.x * 256 + threadIdx.x;
  if (seq >= B_ * IN_) return;
  const float2* pp = part + (size_t)seq * NCH_;
  float P = 0.0f, Mx = -INFINITY, Ss = 0.0f;
  for (int c = 0; c < NCH_; ++c) {
    const float2 al = pp[c];
    const float v = al.y - P;
    const float m = fmaxf(Mx, v);
    Ss = Ss * __builtin_amdgcn_exp2f(Mx - m) + __builtin_amdgcn_exp2f(v - m);
    Mx = m;
    P += al.x;
  }
  hlast[seq] = __builtin_amdgcn_exp2f(P + Mx) * Ss;
}

// ---------------------------------------------------------------------------
// G = (h_last + skip*act) * silu(z), written in place over the z buffer.
// ---------------------------------------------------------------------------
__launch_bounds__(256)
__global__ void gfuse_k(const unsigned* __restrict__ actb,
                        unsigned* __restrict__ zb,
                        const float* __restrict__ hlast,
                        const float* __restrict__ skipv)
{
  const size_t total  = (size_t)B_ * S_ * IN_ / 8;
  const size_t stride = (size_t)gridDim.x * blockDim.x;
  for (size_t t = (size_t)blockIdx.x * blockDim.x + threadIdx.x; t < total; t += stride) {
    const size_t e = t * 8;
    const int    c = (int)(e % IN_);
    const int    b = (int)(e / ((size_t)S_ * IN_));
    float a[8], z[8], hl[8], sk[8];
    unpack_h8(*(const uint4*)(actb + e / 2), a);
    unpack_h8(*(const uint4*)(zb   + e / 2), z);
    *(float4*)(hl)     = *(const float4*)(hlast + (size_t)b * IN_ + c);
    *(float4*)(hl + 4) = *(const float4*)(hlast + (size_t)b * IN_ + c + 4);
    *(float4*)(sk)     = *(const float4*)(skipv + c);
    *(float4*)(sk + 4) = *(const float4*)(skipv + c + 4);
    float g[8];
    #pragma unroll
    for (int j = 0; j < 8; ++j) g[j] = (hl[j] + sk[j] * a[j]) * z[j];
    uint4 o;
    o.x = packh2(g[0], g[1]);
    o.y = packh2(g[2], g[3]);
    o.z = packh2(g[4], g[5]);
    o.w = packh2(g[6], g[7]);
    *(uint4*)(zb + e / 2) = o;
  }
}

// ---------------------------------------------------------------------------
extern "C" void kernel_launch(void* const* d_in, const int* in_sizes, int n_in,
                              void* d_out, int out_size, void* d_ws, size_t ws_size,
                              hipStream_t stream)
{
  const float* x     = (const float*)d_in[0];
  const float* w_up  = (const float*)d_in[1];
  const float* b_up  = (const float*)d_in[2];
  const float* cw    = (const float*)d_in[3];
  const float* cb    = (const float*)d_in[4];
  const float* skipv = (const float*)d_in[5];
  const float* w_f   = (const float*)d_in[6];
  const float* w_i   = (const float*)d_in[7];
  const float* w_h   = (const float*)d_in[8];
  const float* w_dn  = (const float*)d_in[9];
  const float* b_dn  = (const float*)d_in[10];
  float* out = (float*)d_out;

  // workspace layout with lifetime-based aliasing (max ~210 MB):
  //  [0,   67M): xminb (dead after conv) -> then bpd @0 (4MB),
  //              part @8.39M (8.39MB), hlast @16.78M (32KB)
  //  [67M, 134M): zb (silu(z) -> G in place via gfuse)
  //  [134M,201M): actb;  xb (f16 x, 33.5M) aliases this region (dead pre-conv)
  //  [201M,209.4M): bpu (8MB packed w_up)
  char* ws = (char*)d_ws;
  unsigned short* xminb = (unsigned short*)(ws);
  uint4*          bpd   = (uint4*)(ws);                             // after conv
  float2*         part  = (float2*)(ws + 8388608ULL);               // after conv
  float*          hlast = (float*)(ws + 16777216ULL);               // after conv
  unsigned short* zb    = (unsigned short*)(ws + 67108864ULL);
  unsigned short* actb  = (unsigned short*)(ws + 134217728ULL);
  unsigned short* xb    = (unsigned short*)(ws + 134217728ULL);     // pre-conv alias
  uint4*          bpu   = (uint4*)(ws + 201326592ULL);

  const int M = B_ * S_;   // 16384

  // 0) x -> f16, w_up -> packed fragment tiles
  cvt_f16<<<2048, 256, 0, stream>>>(x, (unsigned*)xb, (long)M * D_ / 8);
  pack_b<<<(2 * IN_ * D_ / 8) / 256, 256, 0, stream>>>(w_up, bpu, D_);

  // 1) proj-up: xb @ w_up^T + b_up -> xmin(f16) | silu(z)(f16)
  gemm_bl2<0><<<dim3((2 * IN_) / 256, M / 128), 512, 0, stream>>>(
      xb, (const unsigned short*)bpu, b_up, xminb, (unsigned short*)zb,
      M, 2 * IN_, D_);

  // 2) causal depthwise conv + SiLU -> act(f16)
  conv_silu_k<<<(B_ * (S_ / 4) * (IN_ / 8)) / 256, 256, 0, stream>>>(
      (const uint4*)xminb, cw, cb, (uint4*)actb);

  // 2b) w_down -> packed fragment tiles (into region freed by xminb)
  pack_b<<<(D_ * IN_ / 8) / 256, 256, 0, stream>>>(w_dn, bpd, IN_);

  // 3) grouped gate projections + chunked scan partials
  gates_scan<<<(B_ * 128 * 16 * NCH_) / 256, 256, 0, stream>>>(
      (const unsigned*)actb, w_f, w_i, w_h, part);

  // 4) combine partials -> h_last
  combine_k<<<(B_ * IN_ + 255) / 256, 256, 0, stream>>>(part, hlast);

  // 5) G = (h_last + skip*act) * silu(z), in place over zb
  gfuse_k<<<2048, 256, 0, stream>>>((const unsigned*)actb, (unsigned*)zb, hlast, skipv);

  // 6) proj-down: G(f16) @ w_dn^T + b_dn -> out (fp32)
  gemm_bl2<1><<<dim3(D_ / 256, M / 128), 512, 0, stream>>>(
      zb, (const unsigned short*)bpd, b_dn, out, nullptr, M, D_, IN_);
}

// Round 13
// 395.581 us; speedup vs baseline: 1.0631x; 1.0489x over previous
//
#include <hip/hip_runtime.h>
#include <math.h>

// ---- problem constants (from reference) ----
constexpr int B_  = 4;
constexpr int S_  = 4096;
constexpr int D_  = 1024;   // DIM
constexpr int IN_ = 2048;   // INNER
constexpr float EPS_ = 1e-8f;
constexpr int NCH_ = 128;         // chunks per sequence for the scan
constexpr int CS_  = S_ / NCH_;   // 32 timesteps per chunk
constexpr float LOG2E_ = 1.4426950408889634f;
constexpr float EPS2_  = 1.4426950408889634e-8f;   // EPS * log2(e)
constexpr float OFF_   = 30.0f;                    // fixed LSE offset (base-2)

typedef __attribute__((ext_vector_type(8))) _Float16 f16x8;
typedef __attribute__((ext_vector_type(2))) _Float16 h2;
typedef __attribute__((ext_vector_type(4))) float    f32x4;

#define BAR() asm volatile("s_barrier" ::: "memory")

// ---- helpers ----
__device__ __forceinline__ h2 pkrtz(float a, float b) {
  auto r = __builtin_amdgcn_cvt_pkrtz(a, b);
  union { decltype(r) r_; h2 h; } c; c.r_ = r; return c.h;
}
__device__ __forceinline__ unsigned packh2(float a, float b) {
  auto r = __builtin_amdgcn_cvt_pkrtz(a, b);
  union { decltype(r) r_; unsigned u; } c; c.r_ = r; return c.u;
}
__device__ __forceinline__ void unpack_h8(uint4 v, float* f) {
  union { uint4 u; _Float16 h[8]; } c; c.u = v;
  #pragma unroll
  for (int i = 0; i < 8; ++i) f[i] = (float)c.h[i];
}
// base-2 softplus: sp2(t) = max(t,0) + log2(1 + 2^-|t|)
__device__ __forceinline__ float sp2(float t) {
  const float e = __builtin_amdgcn_exp2f(-fabsf(t));
  return fmaxf(t, 0.0f) + __builtin_amdgcn_logf(1.0f + e);
}
__device__ __forceinline__ float siluf(float x) {
  return x * __builtin_amdgcn_rcpf(1.0f + __builtin_amdgcn_exp2f(-x * LOG2E_));
}

// async global->LDS, 16 B per lane (wave-uniform LDS base + lane*16)
__device__ __forceinline__ void gload16(const void* g, void* l) {
  __builtin_amdgcn_global_load_lds(
      (const __attribute__((address_space(1))) void*)g,
      (__attribute__((address_space(3))) void*)l,
      16, 0, 0);
}

// ---------------------------------------------------------------------------
// fp32 -> f16 conversion for two buffers in one launch (8 elems/thread)
// ---------------------------------------------------------------------------
__launch_bounds__(256)
__global__ void cvt_f16_2(const float* __restrict__ in0, unsigned* __restrict__ out0,
                          long n8_0,
                          const float* __restrict__ in1, unsigned* __restrict__ out1,
                          long n8_1)
{
  const long total  = n8_0 + n8_1;
  const long stride = (long)gridDim.x * blockDim.x;
  for (long t = (long)blockIdx.x * blockDim.x + threadIdx.x; t < total; t += stride) {
    const float* in  = (t < n8_0) ? in0  : in1;
    unsigned*    out = (t < n8_0) ? out0 : out1;
    const long   i   = (t < n8_0) ? t    : t - n8_0;
    const float4 a = *(const float4*)(in + i * 8);
    const float4 b = *(const float4*)(in + i * 8 + 4);
    uint4 o;
    o.x = packh2(a.x, a.y);
    o.y = packh2(a.z, a.w);
    o.z = packh2(b.x, b.y);
    o.w = packh2(b.z, b.w);
    *(uint4*)(out + i * 4) = o;
  }
}

__launch_bounds__(256)
__global__ void cvt_f16(const float* __restrict__ in, unsigned* __restrict__ outp,
                        long n8)
{
  const long stride = (long)gridDim.x * blockDim.x;
  for (long i = (long)blockIdx.x * blockDim.x + threadIdx.x; i < n8; i += stride) {
    const float4 a = *(const float4*)(in + i * 8);
    const float4 b = *(const float4*)(in + i * 8 + 4);
    uint4 o;
    o.x = packh2(a.x, a.y);
    o.y = packh2(a.z, a.w);
    o.z = packh2(b.x, b.y);
    o.w = packh2(b.z, b.w);
    *(uint4*)(outp + i * 4) = o;
  }
}

// ---------------------------------------------------------------------------
// f16 MFMA NT GEMM, 4-phase schedule, 256x256 tile, BK=64, 8 waves (2Mx4N),
// double-buffered LDS (128 KiB), XOR-16B-block swizzle, counted vmcnt(8),
// setprio, bijective XCD swizzle, staging spread 2-2-4 across phases 1/2/3.
// (r10 configuration — best measured: 164 us proj-up, ~85 us proj-down)
// MODE 0: split epilogue -> xmin(f16) | silu(z)(f16) via per-wave LDS
//         transpose (16B full-line stores).
// MODE 1: fp32 out, direct stores (64B-contiguous per 16 lanes).
// ---------------------------------------------------------------------------
template<int MODE>
__launch_bounds__(512, 2)
__global__ void gemm_mfma(const unsigned short* __restrict__ Ab,
                          const unsigned short* __restrict__ Bb,
                          const float* __restrict__ bias,
                          void* __restrict__ out0,
                          unsigned short* __restrict__ out1,
                          int M, int N, int K)
{
  constexpr int BM = 256, BN = 256, BK = 64;
  __shared__ __align__(16) unsigned short As[2][BM * BK];  // 2 x 32 KB
  __shared__ __align__(16) unsigned short Bs[2][BN * BK];  // 2 x 32 KB

  const int tid  = threadIdx.x;
  const int lane = tid & 63;
  const int w    = tid >> 6;       // 0..7
  const int wm   = w >> 2;         // 0..1  (M half)
  const int wn   = w & 3;          // 0..3  (N quarter)

  // bijective XCD swizzle
  const int GX  = gridDim.x;
  const int nwg = GX * gridDim.y;           // divisible by 8 for our shapes
  int lin = blockIdx.y * GX + blockIdx.x;
  lin = (lin & 7) * (nwg >> 3) + (lin >> 3);
  const int m0 = (lin / GX) * BM;
  const int n0 = (lin % GX) * BN;
  const int NT = K / BK;

  // staging geometry
  const int sr   = lane >> 3;                   // 0..7 row-in-slice
  const int sblk = ((lane & 7) ^ sr) * 8;       // pre-swizzled global col

  // fragment read geometry
  const int fr  = lane & 15;
  const int fb0 = (((lane >> 4) + 0) ^ (lane & 7)) * 8;
  const int fb1 = (((lane >> 4) + 4) ^ (lane & 7)) * 8;

  auto stage64 = [&](const unsigned short* Gp, int Kd, int grow0, int kOff,
                     unsigned short* lchunk) {
    gload16(Gp + (size_t)(grow0 + w * 8 + sr) * Kd + kOff + sblk,
            lchunk + (w * 8) * BK);
  };

  f32x4 acc[8][4] = {};

  // ---- prologue: stage tiles 0 and 1 ----
  #pragma unroll
  for (int c = 0; c < 4; ++c) stage64(Ab, K, m0 + c * 64, 0, &As[0][c * 64 * BK]);
  #pragma unroll
  for (int c = 0; c < 4; ++c) stage64(Bb, K, n0 + c * 64, 0, &Bs[0][c * 64 * BK]);
  #pragma unroll
  for (int c = 0; c < 4; ++c) stage64(Ab, K, m0 + c * 64, BK, &As[1][c * 64 * BK]);
  #pragma unroll
  for (int c = 0; c < 4; ++c) stage64(Bb, K, n0 + c * 64, BK, &Bs[1][c * 64 * BK]);
  asm volatile("s_waitcnt vmcnt(8)" ::: "memory");   // tile 0 landed
  BAR();

  for (int t = 0; t < NT; ++t) {
    const int cur = t & 1;
    const unsigned short* AL = As[cur];
    const unsigned short* BL = Bs[cur];
    const int  nxtK = (t + 2) * BK;
    const bool more = (t + 2 < NT);

    f16x8 af[4][2], bf[4][2];

    // ---- phase 0: quadrant (mq=0, nq=0) — 12 ds_reads, 16 MFMA
    #pragma unroll
    for (int i = 0; i < 4; ++i) {
      const int row = wm * 128 + i * 16 + fr;
      af[i][0] = *(const f16x8*)&AL[row * BK + fb0];
      af[i][1] = *(const f16x8*)&AL[row * BK + fb1];
    }
    #pragma unroll
    for (int j = 0; j < 2; ++j) {
      const int row = wn * 64 + j * 16 + fr;
      bf[j][0] = *(const f16x8*)&BL[row * BK + fb0];
      bf[j][1] = *(const f16x8*)&BL[row * BK + fb1];
    }
    BAR();
    __builtin_amdgcn_s_setprio(1);
    #pragma unroll
    for (int i = 0; i < 4; ++i)
      #pragma unroll
      for (int j = 0; j < 2; ++j) {
        acc[i][j] = __builtin_amdgcn_mfma_f32_16x16x32_f16(af[i][0], bf[j][0], acc[i][j], 0, 0, 0);
        acc[i][j] = __builtin_amdgcn_mfma_f32_16x16x32_f16(af[i][1], bf[j][1], acc[i][j], 0, 0, 0);
      }
    __builtin_amdgcn_s_setprio(0);
    BAR();

    // ---- phase 1: (mq=0, nq=1) — 4 ds_reads; stage A chunks 0,2 of t+2
    #pragma unroll
    for (int j = 2; j < 4; ++j) {
      const int row = wn * 64 + j * 16 + fr;
      bf[j][0] = *(const f16x8*)&BL[row * BK + fb0];
      bf[j][1] = *(const f16x8*)&BL[row * BK + fb1];
    }
    if (more) {
      stage64(Ab, K, m0 +   0, nxtK, &As[cur][0]);
      stage64(Ab, K, m0 + 128, nxtK, &As[cur][128 * BK]);
    }
    BAR();
    __builtin_amdgcn_s_setprio(1);
    #pragma unroll
    for (int i = 0; i < 4; ++i)
      #pragma unroll
      for (int j = 2; j < 4; ++j) {
        acc[i][j] = __builtin_amdgcn_mfma_f32_16x16x32_f16(af[i][0], bf[j][0], acc[i][j], 0, 0, 0);
        acc[i][j] = __builtin_amdgcn_mfma_f32_16x16x32_f16(af[i][1], bf[j][1], acc[i][j], 0, 0, 0);
      }
    __builtin_amdgcn_s_setprio(0);
    BAR();

    // ---- phase 2: (mq=1, nq=0) — 8 ds_reads; stage B chunks 0,1 of t+2
    #pragma unroll
    for (int i = 0; i < 4; ++i) {
      const int row = wm * 128 + 64 + i * 16 + fr;
      af[i][0] = *(const f16x8*)&AL[row * BK + fb0];
      af[i][1] = *(const f16x8*)&AL[row * BK + fb1];
    }
    if (more) {
      stage64(Bb, K, n0 +   0, nxtK, &Bs[cur][0]);
      stage64(Bb, K, n0 +  64, nxtK, &Bs[cur][64 * BK]);
    }
    BAR();
    __builtin_amdgcn_s_setprio(1);
    #pragma unroll
    for (int i = 0; i < 4; ++i)
      #pragma unroll
      for (int j = 0; j < 2; ++j) {
        acc[4 + i][j] = __builtin_amdgcn_mfma_f32_16x16x32_f16(af[i][0], bf[j][0], acc[4 + i][j], 0, 0, 0);
        acc[4 + i][j] = __builtin_amdgcn_mfma_f32_16x16x32_f16(af[i][1], bf[j][1], acc[4 + i][j], 0, 0, 0);
      }
    __builtin_amdgcn_s_setprio(0);
    BAR();

    // ---- phase 3: (mq=1, nq=1) — 0 ds_reads; stage A chunks 1,3 + B chunks 2,3
    if (more) {
      stage64(Ab, K, m0 +  64, nxtK, &As[cur][64 * BK]);
      stage64(Ab, K, m0 + 192, nxtK, &As[cur][192 * BK]);
      stage64(Bb, K, n0 + 128, nxtK, &Bs[cur][128 * BK]);
      stage64(Bb, K, n0 + 192, nxtK, &Bs[cur][192 * BK]);
    }
    BAR();
    __builtin_amdgcn_s_setprio(1);
    #pragma unroll
    for (int i = 0; i < 4; ++i)
      #pragma unroll
      for (int j = 2; j < 4; ++j) {
        acc[4 + i][j] = __builtin_amdgcn_mfma_f32_16x16x32_f16(af[i][0], bf[j][0], acc[4 + i][j], 0, 0, 0);
        acc[4 + i][j] = __builtin_amdgcn_mfma_f32_16x16x32_f16(af[i][1], bf[j][1], acc[4 + i][j], 0, 0, 0);
      }
    __builtin_amdgcn_s_setprio(0);
    if (more) asm volatile("s_waitcnt vmcnt(8)" ::: "memory");
    else      asm volatile("s_waitcnt vmcnt(0)" ::: "memory");
    BAR();
  }

  // ---- epilogue ----
  const int col = lane & 15;
  const int rb4 = (lane >> 4) * 4;

  if (MODE == 1) {
    #pragma unroll
    for (int j = 0; j < 4; ++j) {
      const int n  = n0 + wn * 64 + j * 16 + col;
      const float bv = bias[n];
      #pragma unroll
      for (int i = 0; i < 8; ++i) {
        const int mb = m0 + wm * 128 + i * 16 + rb4;
        #pragma unroll
        for (int r = 0; r < 4; ++r)
          ((float*)out0)[(size_t)(mb + r) * N + n] = acc[i][j][r] + bv;
      }
    }
  } else {
    // f16 split outputs via per-wave LDS transpose -> 16B full-line stores.
    constexpr int RS = 72;
    unsigned short* eb = (w < 4) ? ((unsigned short*)As + w * (64 * RS))
                                 : ((unsigned short*)Bs + (w - 4) * (64 * RS));
    const bool zhalf = (n0 >= IN_);   // block-uniform
    float bv[4];
    #pragma unroll
    for (int j = 0; j < 4; ++j) bv[j] = bias[n0 + wn * 64 + j * 16 + col];

    const int lrow = lane >> 3;
    const int lc8  = (lane & 7) * 8;
    unsigned short* dst = zhalf ? out1 : (unsigned short*)out0;
    const int ncol0 = (zhalf ? n0 - IN_ : n0) + wn * 64 + lc8;

    #pragma unroll
    for (int h = 0; h < 2; ++h) {
      asm volatile("s_waitcnt lgkmcnt(0)" ::: "memory");
      #pragma unroll
      for (int i2 = 0; i2 < 4; ++i2)
        #pragma unroll
        for (int j = 0; j < 4; ++j)
          #pragma unroll
          for (int r = 0; r < 4; ++r) {
            const float v = acc[h * 4 + i2][j][r] + bv[j];
            ((_Float16*)eb)[(i2 * 16 + rb4 + r) * RS + j * 16 + col] = (_Float16)v;
          }
      asm volatile("s_waitcnt lgkmcnt(0)" ::: "memory");
      #pragma unroll
      for (int it = 0; it < 8; ++it) {
        const int row = it * 8 + lrow;
        uint4 d = *(const uint4*)&eb[row * RS + lc8];
        if (zhalf) {
          float f[8];
          unpack_h8(d, f);
          d.x = packh2(siluf(f[0]), siluf(f[1]));
          d.y = packh2(siluf(f[2]), siluf(f[3]));
          d.z = packh2(siluf(f[4]), siluf(f[5]));
          d.w = packh2(siluf(f[6]), siluf(f[7]));
        }
        const int m = m0 + wm * 128 + h * 64 + row;
        *(uint4*)(dst + (size_t)m * IN_ + ncol0) = d;
      }
    }
  }
}

// ---------------------------------------------------------------------------
// causal depthwise conv (K=4, left pad 3) + SiLU.  f16 in/out.
// 8 channels x 4 timesteps per thread: 7 row-loads for 4 outputs.
// ---------------------------------------------------------------------------
__launch_bounds__(256)
__global__ void conv_silu_k(const uint4* __restrict__ xm,
                            const float* __restrict__ cw,   // (IN_,1,4)
                            const float* __restrict__ cb,
                            uint4* __restrict__ act)
{
  const int t = blockIdx.x * 256 + threadIdx.x;   // grid sized exactly
  const int c8 = t & 255;                         // channel group (IN_/8)
  const int s4 = (t >> 8) & (S_ / 4 - 1);         // timestep group
  const int b  = t >> 18;
  const int c  = c8 * 8;
  constexpr int RW = IN_ / 8;                     // row stride in uint4

  float w[8][4];
  #pragma unroll
  for (int j = 0; j < 8; ++j)
    *(float4*)w[j] = *(const float4*)(cw + (size_t)(c + j) * 4);
  float bias8[8];
  *(float4*)(bias8)     = *(const float4*)(cb + c);
  *(float4*)(bias8 + 4) = *(const float4*)(cb + c + 4);

  const size_t rowb = ((size_t)b * S_ + s4 * 4) * RW + c8;
  float xf[7][8];
  #pragma unroll
  for (int i = 0; i < 7; ++i) {
    if (s4 == 0 && i < 3) {
      #pragma unroll
      for (int j = 0; j < 8; ++j) xf[i][j] = 0.0f;
    } else {
      unpack_h8(xm[rowb + (long)(i - 3) * RW], xf[i]);
    }
  }

  #pragma unroll
  for (int o = 0; o < 4; ++o) {
    float r[8];
    #pragma unroll
    for (int j = 0; j < 8; ++j) r[j] = bias8[j];
    #pragma unroll
    for (int k = 0; k < 4; ++k)
      #pragma unroll
      for (int j = 0; j < 8; ++j)
        r[j] = fmaf(xf[o + k][j], w[j][k], r[j]);
    uint4 ov;
    ov.x = packh2(siluf(r[0]), siluf(r[1]));
    ov.y = packh2(siluf(r[2]), siluf(r[3]));
    ov.z = packh2(siluf(r[4]), siluf(r[5]));
    ov.w = packh2(siluf(r[6]), siluf(r[7]));
    act[rowb + (size_t)o * RW] = ov;
  }
}

// ---------------------------------------------------------------------------
// grouped 16x16 gate projections + per-chunk scan partials, base-2 domain.
// BACKWARD iteration with suffix-sum q: the LSE argument w = li + lth + q
// is bounded above (li<=0, lth<=~36, q<=~0), so a FIXED offset replaces the
// online max entirely: Ss += exp2(w - OFF).  L = -P + OFF + log2(Ss).
// ---------------------------------------------------------------------------
__launch_bounds__(256)
__global__ void gates_scan(const unsigned* __restrict__ actb,
                           const float* __restrict__ wf,
                           const float* __restrict__ wi,
                           const float* __restrict__ wh,
                           float2* __restrict__ part)   // [B_*IN_][NCH_]
{
  const int T  = blockIdx.x * 256 + threadIdx.x;
  const int o  = T & 15;
  const int g  = (T >> 4) & 127;
  const int ck = (T >> 11) & (NCH_ - 1);
  const int b  = T >> 18;

  h2 Wf2[8], Wi2[8], Wh2[8];
  const float* pf = wf + ((size_t)g * 16 + o) * 16;
  const float* pi = wi + ((size_t)g * 16 + o) * 16;
  const float* ph = wh + ((size_t)g * 16 + o) * 16;
  #pragma unroll
  for (int i = 0; i < 8; ++i) {
    Wf2[i] = pkrtz(pf[2 * i] * LOG2E_, pf[2 * i + 1] * LOG2E_);
    Wi2[i] = pkrtz(pi[2 * i] * LOG2E_, pi[2 * i + 1] * LOG2E_);
    Wh2[i] = pkrtz(ph[2 * i], ph[2 * i + 1]);
  }

  float q = 0.0f, Ss = 0.0f;
  // start at the LAST step of the chunk, walk backward
  const unsigned* ap = actb + ((size_t)b * S_ + (size_t)ck * CS_ + (CS_ - 1)) * (IN_ / 2) + g * 8;
  for (int s = 0; s < CS_; ++s) {
    union { uint4 u; h2 h[4]; } A0, A1;
    A0.u = *(const uint4*)(ap);
    A1.u = *(const uint4*)(ap + 4);
    ap -= IN_ / 2;
    float fg = 0.0f, ig = 0.0f, hd = 0.0f;   // fg, ig in base-2 units
    #pragma unroll
    for (int i = 0; i < 4; ++i) {
      fg = __builtin_amdgcn_fdot2(A0.h[i], Wf2[i], fg, false);
      ig = __builtin_amdgcn_fdot2(A0.h[i], Wi2[i], ig, false);
      hd = __builtin_amdgcn_fdot2(A0.h[i], Wh2[i], hd, false);
    }
    #pragma unroll
    for (int i = 0; i < 4; ++i) {
      fg = __builtin_amdgcn_fdot2(A1.h[i], Wf2[i + 4], fg, false);
      ig = __builtin_amdgcn_fdot2(A1.h[i], Wi2[i + 4], ig, false);
      hd = __builtin_amdgcn_fdot2(A1.h[i], Wh2[i + 4], hd, false);
    }
    const float diff  = sp2(-fg) - sp2(-ig);
    const float log_f = -sp2(diff);
    const float log_i = diff + log_f;          // sp2(-d) = sp2(d) - d
    const float lpos  = __builtin_amdgcn_logf(hd + 0.5f + EPS_);
    const float lneg  = -sp2(-hd * LOG2E_) + EPS2_;
    const float log_th = (hd >= 0.0f) ? lpos : lneg;
    Ss += __builtin_amdgcn_exp2f(log_i + log_th + q - OFF_);
    q += log_f + EPS2_;
  }
  // P_ck = q;  L_ck = -P + OFF + log2(Ss)  (1e-44 guards log2(0) -> finite)
  part[((size_t)(b * IN_ + g * 16 + o)) * NCH_ + ck] =
      make_float2(q, -q + OFF_ + __builtin_amdgcn_logf(Ss + 1e-44f));
}

// ---------------------------------------------------------------------------
// combine chunk partials -> h_last[b, c]   (base-2 domain throughout)
// ---------------------------------------------------------------------------
__launch_bounds__(256)
__global__ void combine_k(const float2* __restrict__ part, float* __restrict__ hlast)
{
  const int seq = blockIdx.x * 256 + threadIdx.x;
  if (seq >= B_ * IN_) return;
  const float2* pp = part + (size_t)seq * NCH_;
  float P = 0.0f, Mx = -INFINITY, Ss = 0.0f;
  for (int c = 0; c < NCH_; ++c) {
    const float2 al = pp[c];
    const float v = al.y - P;
    const float m = fmaxf(Mx, v);
    Ss = Ss * __builtin_amdgcn_exp2f(Mx - m) + __builtin_amdgcn_exp2f(v - m);
    Mx = m;
    P += al.x;
  }
  hlast[seq] = __builtin_amdgcn_exp2f(P + Mx) * Ss;
}

// ---------------------------------------------------------------------------
// G = (h_last + skip*act) * silu(z), written in place over the z buffer.
// ---------------------------------------------------------------------------
__launch_bounds__(256)
__global__ void gfuse_k(const unsigned* __restrict__ actb,
                        unsigned* __restrict__ zb,
                        const float* __restrict__ hlast,
                        const float* __restrict__ skipv)
{
  const size_t total  = (size_t)B_ * S_ * IN_ / 8;
  const size_t stride = (size_t)gridDim.x * blockDim.x;
  for (size_t t = (size_t)blockIdx.x * blockDim.x + threadIdx.x; t < total; t += stride) {
    const size_t e = t * 8;
    const int    c = (int)(e % IN_);
    const int    b = (int)(e / ((size_t)S_ * IN_));
    float a[8], z[8], hl[8], sk[8];
    unpack_h8(*(const uint4*)(actb + e / 2), a);
    unpack_h8(*(const uint4*)(zb   + e / 2), z);
    *(float4*)(hl)     = *(const float4*)(hlast + (size_t)b * IN_ + c);
    *(float4*)(hl + 4) = *(const float4*)(hlast + (size_t)b * IN_ + c + 4);
    *(float4*)(sk)     = *(const float4*)(skipv + c);
    *(float4*)(sk + 4) = *(const float4*)(skipv + c + 4);
    float g[8];
    #pragma unroll
    for (int j = 0; j < 8; ++j) g[j] = (hl[j] + sk[j] * a[j]) * z[j];
    uint4 o;
    o.x = packh2(g[0], g[1]);
    o.y = packh2(g[2], g[3]);
    o.z = packh2(g[4], g[5]);
    o.w = packh2(g[6], g[7]);
    *(uint4*)(zb + e / 2) = o;
  }
}

// ---------------------------------------------------------------------------
extern "C" void kernel_launch(void* const* d_in, const int* in_sizes, int n_in,
                              void* d_out, int out_size, void* d_ws, size_t ws_size,
                              hipStream_t stream)
{
  const float* x     = (const float*)d_in[0];
  const float* w_up  = (const float*)d_in[1];
  const float* b_up  = (const float*)d_in[2];
  const float* cw    = (const float*)d_in[3];
  const float* cb    = (const float*)d_in[4];
  const float* skipv = (const float*)d_in[5];
  const float* w_f   = (const float*)d_in[6];
  const float* w_i   = (const float*)d_in[7];
  const float* w_h   = (const float*)d_in[8];
  const float* w_dn  = (const float*)d_in[9];
  const float* b_dn  = (const float*)d_in[10];
  float* out = (float*)d_out;

  // workspace layout with lifetime-based aliasing (max ~210 MB)
  char* ws = (char*)d_ws;
  unsigned short* xminb = (unsigned short*)(ws);
  unsigned short* wdb   = (unsigned short*)(ws);                    // after conv
  float2*         part  = (float2*)(ws + 8388608ULL);               // after conv
  float*          hlast = (float*)(ws + 16777216ULL);               // after conv
  unsigned short* zb    = (unsigned short*)(ws + 67108864ULL);
  unsigned short* actb  = (unsigned short*)(ws + 134217728ULL);
  unsigned short* xb    = (unsigned short*)(ws + 134217728ULL);     // pre-conv alias
  unsigned short* wub   = (unsigned short*)(ws + 201326592ULL);

  const int M = B_ * S_;   // 16384

  // 0) fp32 -> f16 conversions for MFMA operands (single launch)
  cvt_f16_2<<<2560, 256, 0, stream>>>(
      x,    (unsigned*)xb,  (long)M * D_ / 8,
      w_up, (unsigned*)wub, (long)2 * IN_ * D_ / 8);

  // 1) proj-up: xb @ wub^T + b_up -> xmin(f16) | silu(z)(f16)
  gemm_mfma<0><<<dim3((2 * IN_) / 256, M / 256), 512, 0, stream>>>(
      xb, wub, b_up, xminb, (unsigned short*)zb, M, 2 * IN_, D_);

  // 2) causal depthwise conv + SiLU -> act(f16)  (4 steps x 8 ch / thread)
  conv_silu_k<<<(B_ * (S_ / 4) * (IN_ / 8)) / 256, 256, 0, stream>>>(
      (const uint4*)xminb, cw, cb, (uint4*)actb);

  // 2b) w_down -> f16 (into region freed by xminb)
  cvt_f16<<<256, 256, 0, stream>>>(w_dn, (unsigned*)wdb, (long)D_ * IN_ / 8);

  // 3) grouped gate projections + chunked scan partials (backward, fixed-off)
  gates_scan<<<(B_ * 128 * 16 * NCH_) / 256, 256, 0, stream>>>(
      (const unsigned*)actb, w_f, w_i, w_h, part);

  // 4) combine partials -> h_last
  combine_k<<<(B_ * IN_ + 255) / 256, 256, 0, stream>>>(part, hlast);

  // 5) G = (h_last + skip*act) * silu(z), in place over zb
  gfuse_k<<<2048, 256, 0, stream>>>((const unsigned*)actb, (unsigned*)zb, hlast, skipv);

  // 6) proj-down: G(f16) @ wdb^T + b_dn -> out (fp32)
  gemm_mfma<1><<<dim3(D_ / 256, M / 256), 512, 0, stream>>>(
      zb, wdb, b_dn, out, nullptr, M, D_, IN_);
}

// Round 14
// 376.631 us; speedup vs baseline: 1.1166x; 1.0503x over previous
//
#include <hip/hip_runtime.h>
#include <math.h>

// ---- problem constants (from reference) ----
constexpr int B_  = 4;
constexpr int S_  = 4096;
constexpr int D_  = 1024;   // DIM
constexpr int IN_ = 2048;   // INNER
constexpr float EPS_ = 1e-8f;
constexpr int NCH_ = 128;         // chunks per sequence for the scan
constexpr int CS_  = S_ / NCH_;   // 32 timesteps per chunk
constexpr float LOG2E_ = 1.4426950408889634f;

typedef __attribute__((ext_vector_type(8))) _Float16 f16x8;
typedef __attribute__((ext_vector_type(2))) _Float16 h2;
typedef __attribute__((ext_vector_type(4))) float    f32x4;

#define BAR() asm volatile("s_barrier" ::: "memory")

// ---- helpers ----
__device__ __forceinline__ h2 pkrtz(float a, float b) {
  auto r = __builtin_amdgcn_cvt_pkrtz(a, b);
  union { decltype(r) r_; h2 h; } c; c.r_ = r; return c.h;
}
__device__ __forceinline__ unsigned packh2(float a, float b) {
  auto r = __builtin_amdgcn_cvt_pkrtz(a, b);
  union { decltype(r) r_; unsigned u; } c; c.r_ = r; return c.u;
}
__device__ __forceinline__ void unpack_h8(uint4 v, float* f) {
  union { uint4 u; _Float16 h[8]; } c; c.u = v;
  #pragma unroll
  for (int i = 0; i < 8; ++i) f[i] = (float)c.h[i];
}
__device__ __forceinline__ float siluf(float x) {
  return x * __builtin_amdgcn_rcpf(1.0f + __builtin_amdgcn_exp2f(-x * LOG2E_));
}

// async global->LDS, 16 B per lane (wave-uniform LDS base + lane*16)
__device__ __forceinline__ void gload16(const void* g, void* l) {
  __builtin_amdgcn_global_load_lds(
      (const __attribute__((address_space(1))) void*)g,
      (__attribute__((address_space(3))) void*)l,
      16, 0, 0);
}

// ---------------------------------------------------------------------------
// fp32 -> f16 conversion for two buffers in one launch (8 elems/thread)
// ---------------------------------------------------------------------------
__launch_bounds__(256)
__global__ void cvt_f16_2(const float* __restrict__ in0, unsigned* __restrict__ out0,
                          long n8_0,
                          const float* __restrict__ in1, unsigned* __restrict__ out1,
                          long n8_1)
{
  const long total  = n8_0 + n8_1;
  const long stride = (long)gridDim.x * blockDim.x;
  for (long t = (long)blockIdx.x * blockDim.x + threadIdx.x; t < total; t += stride) {
    const float* in  = (t < n8_0) ? in0  : in1;
    unsigned*    out = (t < n8_0) ? out0 : out1;
    const long   i   = (t < n8_0) ? t    : t - n8_0;
    const float4 a = *(const float4*)(in + i * 8);
    const float4 b = *(const float4*)(in + i * 8 + 4);
    uint4 o;
    o.x = packh2(a.x, a.y);
    o.y = packh2(a.z, a.w);
    o.z = packh2(b.x, b.y);
    o.w = packh2(b.z, b.w);
    *(uint4*)(out + i * 4) = o;
  }
}

__launch_bounds__(256)
__global__ void cvt_f16(const float* __restrict__ in, unsigned* __restrict__ outp,
                        long n8)
{
  const long stride = (long)gridDim.x * blockDim.x;
  for (long i = (long)blockIdx.x * blockDim.x + threadIdx.x; i < n8; i += stride) {
    const float4 a = *(const float4*)(in + i * 8);
    const float4 b = *(const float4*)(in + i * 8 + 4);
    uint4 o;
    o.x = packh2(a.x, a.y);
    o.y = packh2(a.z, a.w);
    o.z = packh2(b.x, b.y);
    o.w = packh2(b.z, b.w);
    *(uint4*)(outp + i * 4) = o;
  }
}

// ---------------------------------------------------------------------------
// f16 MFMA NT GEMM, 4-phase schedule, 256x256 tile, BK=64, 8 waves (2Mx4N),
// double-buffered LDS (128 KiB), XOR-16B-block swizzle, counted vmcnt(8),
// setprio, bijective XCD swizzle, staging spread 2-2-4 across phases 1/2/3.
// (r10 configuration — best measured: 164 us proj-up, ~85 us proj-down)
// MODE 0: split epilogue -> xmin(f16) | silu(z)(f16) via per-wave LDS
//         transpose (16B full-line stores).
// MODE 1: fp32 out, direct stores (64B-contiguous per 16 lanes).
// ---------------------------------------------------------------------------
template<int MODE>
__launch_bounds__(512, 2)
__global__ void gemm_mfma(const unsigned short* __restrict__ Ab,
                          const unsigned short* __restrict__ Bb,
                          const float* __restrict__ bias,
                          void* __restrict__ out0,
                          unsigned short* __restrict__ out1,
                          int M, int N, int K)
{
  constexpr int BM = 256, BN = 256, BK = 64;
  __shared__ __align__(16) unsigned short As[2][BM * BK];  // 2 x 32 KB
  __shared__ __align__(16) unsigned short Bs[2][BN * BK];  // 2 x 32 KB

  const int tid  = threadIdx.x;
  const int lane = tid & 63;
  const int w    = tid >> 6;       // 0..7
  const int wm   = w >> 2;         // 0..1  (M half)
  const int wn   = w & 3;          // 0..3  (N quarter)

  // bijective XCD swizzle
  const int GX  = gridDim.x;
  const int nwg = GX * gridDim.y;           // divisible by 8 for our shapes
  int lin = blockIdx.y * GX + blockIdx.x;
  lin = (lin & 7) * (nwg >> 3) + (lin >> 3);
  const int m0 = (lin / GX) * BM;
  const int n0 = (lin % GX) * BN;
  const int NT = K / BK;

  // staging geometry
  const int sr   = lane >> 3;                   // 0..7 row-in-slice
  const int sblk = ((lane & 7) ^ sr) * 8;       // pre-swizzled global col

  // fragment read geometry
  const int fr  = lane & 15;
  const int fb0 = (((lane >> 4) + 0) ^ (lane & 7)) * 8;
  const int fb1 = (((lane >> 4) + 4) ^ (lane & 7)) * 8;

  auto stage64 = [&](const unsigned short* Gp, int Kd, int grow0, int kOff,
                     unsigned short* lchunk) {
    gload16(Gp + (size_t)(grow0 + w * 8 + sr) * Kd + kOff + sblk,
            lchunk + (w * 8) * BK);
  };

  f32x4 acc[8][4] = {};

  // ---- prologue: stage tiles 0 and 1 ----
  #pragma unroll
  for (int c = 0; c < 4; ++c) stage64(Ab, K, m0 + c * 64, 0, &As[0][c * 64 * BK]);
  #pragma unroll
  for (int c = 0; c < 4; ++c) stage64(Bb, K, n0 + c * 64, 0, &Bs[0][c * 64 * BK]);
  #pragma unroll
  for (int c = 0; c < 4; ++c) stage64(Ab, K, m0 + c * 64, BK, &As[1][c * 64 * BK]);
  #pragma unroll
  for (int c = 0; c < 4; ++c) stage64(Bb, K, n0 + c * 64, BK, &Bs[1][c * 64 * BK]);
  asm volatile("s_waitcnt vmcnt(8)" ::: "memory");   // tile 0 landed
  BAR();

  for (int t = 0; t < NT; ++t) {
    const int cur = t & 1;
    const unsigned short* AL = As[cur];
    const unsigned short* BL = Bs[cur];
    const int  nxtK = (t + 2) * BK;
    const bool more = (t + 2 < NT);

    f16x8 af[4][2], bf[4][2];

    // ---- phase 0: quadrant (mq=0, nq=0) — 12 ds_reads, 16 MFMA
    #pragma unroll
    for (int i = 0; i < 4; ++i) {
      const int row = wm * 128 + i * 16 + fr;
      af[i][0] = *(const f16x8*)&AL[row * BK + fb0];
      af[i][1] = *(const f16x8*)&AL[row * BK + fb1];
    }
    #pragma unroll
    for (int j = 0; j < 2; ++j) {
      const int row = wn * 64 + j * 16 + fr;
      bf[j][0] = *(const f16x8*)&BL[row * BK + fb0];
      bf[j][1] = *(const f16x8*)&BL[row * BK + fb1];
    }
    BAR();
    __builtin_amdgcn_s_setprio(1);
    #pragma unroll
    for (int i = 0; i < 4; ++i)
      #pragma unroll
      for (int j = 0; j < 2; ++j) {
        acc[i][j] = __builtin_amdgcn_mfma_f32_16x16x32_f16(af[i][0], bf[j][0], acc[i][j], 0, 0, 0);
        acc[i][j] = __builtin_amdgcn_mfma_f32_16x16x32_f16(af[i][1], bf[j][1], acc[i][j], 0, 0, 0);
      }
    __builtin_amdgcn_s_setprio(0);
    BAR();

    // ---- phase 1: (mq=0, nq=1) — 4 ds_reads; stage A chunks 0,2 of t+2
    #pragma unroll
    for (int j = 2; j < 4; ++j) {
      const int row = wn * 64 + j * 16 + fr;
      bf[j][0] = *(const f16x8*)&BL[row * BK + fb0];
      bf[j][1] = *(const f16x8*)&BL[row * BK + fb1];
    }
    if (more) {
      stage64(Ab, K, m0 +   0, nxtK, &As[cur][0]);
      stage64(Ab, K, m0 + 128, nxtK, &As[cur][128 * BK]);
    }
    BAR();
    __builtin_amdgcn_s_setprio(1);
    #pragma unroll
    for (int i = 0; i < 4; ++i)
      #pragma unroll
      for (int j = 2; j < 4; ++j) {
        acc[i][j] = __builtin_amdgcn_mfma_f32_16x16x32_f16(af[i][0], bf[j][0], acc[i][j], 0, 0, 0);
        acc[i][j] = __builtin_amdgcn_mfma_f32_16x16x32_f16(af[i][1], bf[j][1], acc[i][j], 0, 0, 0);
      }
    __builtin_amdgcn_s_setprio(0);
    BAR();

    // ---- phase 2: (mq=1, nq=0) — 8 ds_reads; stage B chunks 0,1 of t+2
    #pragma unroll
    for (int i = 0; i < 4; ++i) {
      const int row = wm * 128 + 64 + i * 16 + fr;
      af[i][0] = *(const f16x8*)&AL[row * BK + fb0];
      af[i][1] = *(const f16x8*)&AL[row * BK + fb1];
    }
    if (more) {
      stage64(Bb, K, n0 +   0, nxtK, &Bs[cur][0]);
      stage64(Bb, K, n0 +  64, nxtK, &Bs[cur][64 * BK]);
    }
    BAR();
    __builtin_amdgcn_s_setprio(1);
    #pragma unroll
    for (int i = 0; i < 4; ++i)
      #pragma unroll
      for (int j = 0; j < 2; ++j) {
        acc[4 + i][j] = __builtin_amdgcn_mfma_f32_16x16x32_f16(af[i][0], bf[j][0], acc[4 + i][j], 0, 0, 0);
        acc[4 + i][j] = __builtin_amdgcn_mfma_f32_16x16x32_f16(af[i][1], bf[j][1], acc[4 + i][j], 0, 0, 0);
      }
    __builtin_amdgcn_s_setprio(0);
    BAR();

    // ---- phase 3: (mq=1, nq=1) — 0 ds_reads; stage A chunks 1,3 + B chunks 2,3
    if (more) {
      stage64(Ab, K, m0 +  64, nxtK, &As[cur][64 * BK]);
      stage64(Ab, K, m0 + 192, nxtK, &As[cur][192 * BK]);
      stage64(Bb, K, n0 + 128, nxtK, &Bs[cur][128 * BK]);
      stage64(Bb, K, n0 + 192, nxtK, &Bs[cur][192 * BK]);
    }
    BAR();
    __builtin_amdgcn_s_setprio(1);
    #pragma unroll
    for (int i = 0; i < 4; ++i)
      #pragma unroll
      for (int j = 2; j < 4; ++j) {
        acc[4 + i][j] = __builtin_amdgcn_mfma_f32_16x16x32_f16(af[i][0], bf[j][0], acc[4 + i][j], 0, 0, 0);
        acc[4 + i][j] = __builtin_amdgcn_mfma_f32_16x16x32_f16(af[i][1], bf[j][1], acc[4 + i][j], 0, 0, 0);
      }
    __builtin_amdgcn_s_setprio(0);
    if (more) asm volatile("s_waitcnt vmcnt(8)" ::: "memory");
    else      asm volatile("s_waitcnt vmcnt(0)" ::: "memory");
    BAR();
  }

  // ---- epilogue ----
  const int col = lane & 15;
  const int rb4 = (lane >> 4) * 4;

  if (MODE == 1) {
    #pragma unroll
    for (int j = 0; j < 4; ++j) {
      const int n  = n0 + wn * 64 + j * 16 + col;
      const float bv = bias[n];
      #pragma unroll
      for (int i = 0; i < 8; ++i) {
        const int mb = m0 + wm * 128 + i * 16 + rb4;
        #pragma unroll
        for (int r = 0; r < 4; ++r)
          ((float*)out0)[(size_t)(mb + r) * N + n] = acc[i][j][r] + bv;
      }
    }
  } else {
    // f16 split outputs via per-wave LDS transpose -> 16B full-line stores.
    constexpr int RS = 72;
    unsigned short* eb = (w < 4) ? ((unsigned short*)As + w * (64 * RS))
                                 : ((unsigned short*)Bs + (w - 4) * (64 * RS));
    const bool zhalf = (n0 >= IN_);   // block-uniform
    float bv[4];
    #pragma unroll
    for (int j = 0; j < 4; ++j) bv[j] = bias[n0 + wn * 64 + j * 16 + col];

    const int lrow = lane >> 3;
    const int lc8  = (lane & 7) * 8;
    unsigned short* dst = zhalf ? out1 : (unsigned short*)out0;
    const int ncol0 = (zhalf ? n0 - IN_ : n0) + wn * 64 + lc8;

    #pragma unroll
    for (int h = 0; h < 2; ++h) {
      asm volatile("s_waitcnt lgkmcnt(0)" ::: "memory");
      #pragma unroll
      for (int i2 = 0; i2 < 4; ++i2)
        #pragma unroll
        for (int j = 0; j < 4; ++j)
          #pragma unroll
          for (int r = 0; r < 4; ++r) {
            const float v = acc[h * 4 + i2][j][r] + bv[j];
            ((_Float16*)eb)[(i2 * 16 + rb4 + r) * RS + j * 16 + col] = (_Float16)v;
          }
      asm volatile("s_waitcnt lgkmcnt(0)" ::: "memory");
      #pragma unroll
      for (int it = 0; it < 8; ++it) {
        const int row = it * 8 + lrow;
        uint4 d = *(const uint4*)&eb[row * RS + lc8];
        if (zhalf) {
          float f[8];
          unpack_h8(d, f);
          d.x = packh2(siluf(f[0]), siluf(f[1]));
          d.y = packh2(siluf(f[2]), siluf(f[3]));
          d.z = packh2(siluf(f[4]), siluf(f[5]));
          d.w = packh2(siluf(f[6]), siluf(f[7]));
        }
        const int m = m0 + wm * 128 + h * 64 + row;
        *(uint4*)(dst + (size_t)m * IN_ + ncol0) = d;
      }
    }
  }
}

// ---------------------------------------------------------------------------
// causal depthwise conv (K=4, left pad 3) + SiLU.  f16 in/out.
// 8 channels x 4 timesteps per thread: 7 row-loads for 4 outputs.
// ---------------------------------------------------------------------------
__launch_bounds__(256)
__global__ void conv_silu_k(const uint4* __restrict__ xm,
                            const float* __restrict__ cw,   // (IN_,1,4)
                            const float* __restrict__ cb,
                            uint4* __restrict__ act)
{
  const int t = blockIdx.x * 256 + threadIdx.x;   // grid sized exactly
  const int c8 = t & 255;                         // channel group (IN_/8)
  const int s4 = (t >> 8) & (S_ / 4 - 1);         // timestep group
  const int b  = t >> 18;
  const int c  = c8 * 8;
  constexpr int RW = IN_ / 8;                     // row stride in uint4

  float w[8][4];
  #pragma unroll
  for (int j = 0; j < 8; ++j)
    *(float4*)w[j] = *(const float4*)(cw + (size_t)(c + j) * 4);
  float bias8[8];
  *(float4*)(bias8)     = *(const float4*)(cb + c);
  *(float4*)(bias8 + 4) = *(const float4*)(cb + c + 4);

  const size_t rowb = ((size_t)b * S_ + s4 * 4) * RW + c8;
  float xf[7][8];
  #pragma unroll
  for (int i = 0; i < 7; ++i) {
    if (s4 == 0 && i < 3) {
      #pragma unroll
      for (int j = 0; j < 8; ++j) xf[i][j] = 0.0f;
    } else {
      unpack_h8(xm[rowb + (long)(i - 3) * RW], xf[i]);
    }
  }

  #pragma unroll
  for (int o = 0; o < 4; ++o) {
    float r[8];
    #pragma unroll
    for (int j = 0; j < 8; ++j) r[j] = bias8[j];
    #pragma unroll
    for (int k = 0; k < 4; ++k)
      #pragma unroll
      for (int j = 0; j < 8; ++j)
        r[j] = fmaf(xf[o + k][j], w[j][k], r[j]);
    uint4 ov;
    ov.x = packh2(siluf(r[0]), siluf(r[1]));
    ov.y = packh2(siluf(r[2]), siluf(r[3]));
    ov.z = packh2(siluf(r[4]), siluf(r[5]));
    ov.w = packh2(siluf(r[6]), siluf(r[7]));
    act[rowb + (size_t)o * RW] = ov;
  }
}

// ---------------------------------------------------------------------------
// grouped 16x16 gate projections + per-chunk scan partials — LINEAR domain.
// Identity: f = (1+E_i)/(2+E_f+E_i), i = (1+E_f)/(2+E_f+E_i) = 1-f, where
// E_f = e^-FG, E_i = e^-IG;  g~ = hd+0.5 (hd>=0) or sigmoid(hd) (hd<0).
// Backward suffix accumulation Ss = sum_t i*g~*2^(q_t) in 4 blocks of 8:
// per block: T += i*g~*R; R *= f  (R >= 2^-33 per block — no underflow);
// close: Ss += exp2(q)*T; q += log2(R).  Exports same (p, L) pair as r13:
// p = q_total, L = -p + log2(Ss).  Only 3 exp2 + 2 rcp per step.
// ---------------------------------------------------------------------------
__launch_bounds__(256)
__global__ void gates_scan(const unsigned* __restrict__ actb,
                           const float* __restrict__ wf,
                           const float* __restrict__ wi,
                           const float* __restrict__ wh,
                           float2* __restrict__ part)   // [B_*IN_][NCH_]
{
  const int T  = blockIdx.x * 256 + threadIdx.x;
  const int o  = T & 15;
  const int g  = (T >> 4) & 127;
  const int ck = (T >> 11) & (NCH_ - 1);
  const int b  = T >> 18;

  h2 Wf2[8], Wi2[8], Wh2[8];
  const float* pf = wf + ((size_t)g * 16 + o) * 16;
  const float* pi = wi + ((size_t)g * 16 + o) * 16;
  const float* ph = wh + ((size_t)g * 16 + o) * 16;
  #pragma unroll
  for (int i = 0; i < 8; ++i) {
    Wf2[i] = pkrtz(pf[2 * i] * LOG2E_, pf[2 * i + 1] * LOG2E_);   // base-2 gates
    Wi2[i] = pkrtz(pi[2 * i] * LOG2E_, pi[2 * i + 1] * LOG2E_);
    Wh2[i] = pkrtz(ph[2 * i], ph[2 * i + 1]);
  }

  float q = 0.0f, Ss = 0.0f;
  // start at the LAST step of the chunk, walk backward in time
  const unsigned* ap = actb + ((size_t)b * S_ + (size_t)ck * CS_ + (CS_ - 1)) * (IN_ / 2) + g * 8;
  for (int blk = 0; blk < 4; ++blk) {
    float R = 1.0f, Tacc = 0.0f;
    #pragma unroll
    for (int s = 0; s < 8; ++s) {
      union { uint4 u; h2 h[4]; } A0, A1;
      A0.u = *(const uint4*)(ap);
      A1.u = *(const uint4*)(ap + 4);
      ap -= IN_ / 2;
      float fg = 0.0f, ig = 0.0f, hd = 0.0f;   // fg, ig in base-2 units
      #pragma unroll
      for (int i = 0; i < 4; ++i) {
        fg = __builtin_amdgcn_fdot2(A0.h[i], Wf2[i], fg, false);
        ig = __builtin_amdgcn_fdot2(A0.h[i], Wi2[i], ig, false);
        hd = __builtin_amdgcn_fdot2(A0.h[i], Wh2[i], hd, false);
      }
      #pragma unroll
      for (int i = 0; i < 4; ++i) {
        fg = __builtin_amdgcn_fdot2(A1.h[i], Wf2[i + 4], fg, false);
        ig = __builtin_amdgcn_fdot2(A1.h[i], Wi2[i + 4], ig, false);
        hd = __builtin_amdgcn_fdot2(A1.h[i], Wh2[i + 4], hd, false);
      }
      const float Ef = __builtin_amdgcn_exp2f(-fg);            // e^-FG
      const float Ei = __builtin_amdgcn_exp2f(-ig);            // e^-IG
      const float rden = __builtin_amdgcn_rcpf(2.0f + Ef + Ei);
      const float f = (1.0f + Ei) * rden;
      const float i = (1.0f + Ef) * rden;
      const float Eh = __builtin_amdgcn_exp2f(-hd * LOG2E_);   // e^-hd
      const float gneg = __builtin_amdgcn_rcpf(1.0f + Eh);     // sigmoid(hd)
      const float gt = (hd >= 0.0f) ? (hd + 0.5f + EPS_) : gneg;
      Tacc = fmaf(i * gt, R, Tacc);
      R *= f;
    }
    Ss = fmaf(__builtin_amdgcn_exp2f(q), Tacc, Ss);
    q += __builtin_amdgcn_logf(R);   // v_log_f32 = log2
  }
  // p = q (log2 of full product);  L = -p + log2(Ss)
  part[((size_t)(b * IN_ + g * 16 + o)) * NCH_ + ck] =
      make_float2(q, -q + __builtin_amdgcn_logf(Ss + 1e-44f));
}

// ---------------------------------------------------------------------------
// combine chunk partials -> h_last[b, c]   (base-2 domain throughout)
// ---------------------------------------------------------------------------
__launch_bounds__(256)
__global__ void combine_k(const float2* __restrict__ part, float* __restrict__ hlast)
{
  const int seq = blockIdx.x * 256 + threadIdx.x;
  if (seq >= B_ * IN_) return;
  const float2* pp = part + (size_t)seq * NCH_;
  float P = 0.0f, Mx = -INFINITY, Ss = 0.0f;
  for (int c = 0; c < NCH_; ++c) {
    const float2 al = pp[c];
    const float v = al.y - P;
    const float m = fmaxf(Mx, v);
    Ss = Ss * __builtin_amdgcn_exp2f(Mx - m) + __builtin_amdgcn_exp2f(v - m);
    Mx = m;
    P += al.x;
  }
  hlast[seq] = __builtin_amdgcn_exp2f(P + Mx) * Ss;
}

// ---------------------------------------------------------------------------
// G = (h_last + skip*act) * silu(z), written in place over the z buffer.
// ---------------------------------------------------------------------------
__launch_bounds__(256)
__global__ void gfuse_k(const unsigned* __restrict__ actb,
                        unsigned* __restrict__ zb,
                        const float* __restrict__ hlast,
                        const float* __restrict__ skipv)
{
  const size_t total  = (size_t)B_ * S_ * IN_ / 8;
  const size_t stride = (size_t)gridDim.x * blockDim.x;
  for (size_t t = (size_t)blockIdx.x * blockDim.x + threadIdx.x; t < total; t += stride) {
    const size_t e = t * 8;
    const int    c = (int)(e % IN_);
    const int    b = (int)(e / ((size_t)S_ * IN_));
    float a[8], z[8], hl[8], sk[8];
    unpack_h8(*(const uint4*)(actb + e / 2), a);
    unpack_h8(*(const uint4*)(zb   + e / 2), z);
    *(float4*)(hl)     = *(const float4*)(hlast + (size_t)b * IN_ + c);
    *(float4*)(hl + 4) = *(const float4*)(hlast + (size_t)b * IN_ + c + 4);
    *(float4*)(sk)     = *(const float4*)(skipv + c);
    *(float4*)(sk + 4) = *(const float4*)(skipv + c + 4);
    float g[8];
    #pragma unroll
    for (int j = 0; j < 8; ++j) g[j] = (hl[j] + sk[j] * a[j]) * z[j];
    uint4 o;
    o.x = packh2(g[0], g[1]);
    o.y = packh2(g[2], g[3]);
    o.z = packh2(g[4], g[5]);
    o.w = packh2(g[6], g[7]);
    *(uint4*)(zb + e / 2) = o;
  }
}

// ---------------------------------------------------------------------------
extern "C" void kernel_launch(void* const* d_in, const int* in_sizes, int n_in,
                              void* d_out, int out_size, void* d_ws, size_t ws_size,
                              hipStream_t stream)
{
  const float* x     = (const float*)d_in[0];
  const float* w_up  = (const float*)d_in[1];
  const float* b_up  = (const float*)d_in[2];
  const float* cw    = (const float*)d_in[3];
  const float* cb    = (const float*)d_in[4];
  const float* skipv = (const float*)d_in[5];
  const float* w_f   = (const float*)d_in[6];
  const float* w_i   = (const float*)d_in[7];
  const float* w_h   = (const float*)d_in[8];
  const float* w_dn  = (const float*)d_in[9];
  const float* b_dn  = (const float*)d_in[10];
  float* out = (float*)d_out;

  // workspace layout with lifetime-based aliasing (max ~210 MB)
  char* ws = (char*)d_ws;
  unsigned short* xminb = (unsigned short*)(ws);
  unsigned short* wdb   = (unsigned short*)(ws);                    // after conv
  float2*         part  = (float2*)(ws + 8388608ULL);               // after conv
  float*          hlast = (float*)(ws + 16777216ULL);               // after conv
  unsigned short* zb    = (unsigned short*)(ws + 67108864ULL);
  unsigned short* actb  = (unsigned short*)(ws + 134217728ULL);
  unsigned short* xb    = (unsigned short*)(ws + 134217728ULL);     // pre-conv alias
  unsigned short* wub   = (unsigned short*)(ws + 201326592ULL);

  const int M = B_ * S_;   // 16384

  // 0) fp32 -> f16 conversions for MFMA operands (single launch)
  cvt_f16_2<<<2560, 256, 0, stream>>>(
      x,    (unsigned*)xb,  (long)M * D_ / 8,
      w_up, (unsigned*)wub, (long)2 * IN_ * D_ / 8);

  // 1) proj-up: xb @ wub^T + b_up -> xmin(f16) | silu(z)(f16)
  gemm_mfma<0><<<dim3((2 * IN_) / 256, M / 256), 512, 0, stream>>>(
      xb, wub, b_up, xminb, (unsigned short*)zb, M, 2 * IN_, D_);

  // 2) causal depthwise conv + SiLU -> act(f16)  (4 steps x 8 ch / thread)
  conv_silu_k<<<(B_ * (S_ / 4) * (IN_ / 8)) / 256, 256, 0, stream>>>(
      (const uint4*)xminb, cw, cb, (uint4*)actb);

  // 2b) w_down -> f16 (into region freed by xminb)
  cvt_f16<<<256, 256, 0, stream>>>(w_dn, (unsigned*)wdb, (long)D_ * IN_ / 8);

  // 3) grouped gate projections + chunked scan partials (linear domain)
  gates_scan<<<(B_ * 128 * 16 * NCH_) / 256, 256, 0, stream>>>(
      (const unsigned*)actb, w_f, w_i, w_h, part);

  // 4) combine partials -> h_last
  combine_k<<<(B_ * IN_ + 255) / 256, 256, 0, stream>>>(part, hlast);

  // 5) G = (h_last + skip*act) * silu(z), in place over zb
  gfuse_k<<<2048, 256, 0, stream>>>((const unsigned*)actb, (unsigned*)zb, hlast, skipv);

  // 6) proj-down: G(f16) @ wdb^T + b_dn -> out (fp32)
  gemm_mfma<1><<<dim3(D_ / 256, M / 256), 512, 0, stream>>>(
      zb, wdb, b_dn, out, nullptr, M, D_, IN_);
}